// Round 2
// baseline (701.854 us; speedup 1.0000x reference)
//
#include <hip/hip_runtime.h>

// PlanePriorNet: P=256 patches x PT=64 pts, D=768. float32 I/O.
// Pipeline: patch_pre -> point_mlp(fp64) -> neighbors(fp64 topk) -> edge_agg -> final_mlp -> plane.
// fp64 only on the chain feeding the discrete top-k; everything else fp32.

#define P 256
#define PT 64
#define NPTS 16384          // P*PT
#define M2N 32768           // 2*N
#define D 768

// ---------------------------------------------------------------- kernel A
// A1d[p][c] = sb1[c] + sum_d lf[p][d]*sw1[d][c]          (double, c<256)
// B1 [p][c] = mb1[c] + sum_d lf[p][d]*mw1[d][c]          (float,  c<512)
__global__ __launch_bounds__(256) void patch_pre(
    const float* __restrict__ lf, const float* __restrict__ sw1,
    const float* __restrict__ sb1, const float* __restrict__ mw1,
    const float* __restrict__ mb1, double* __restrict__ A1d, float* __restrict__ B1) {
  __shared__ double lfs[768];
  const int p = blockIdx.x, t = threadIdx.x;
  for (int i = t; i < 768; i += 256) lfs[i] = (double)lf[p * 768 + i];
  __syncthreads();
  double a = (double)sb1[t];
  float bb0 = 0.f, bb1 = 0.f;
  for (int d = 0; d < 768; ++d) {
    const double l = lfs[d];
    const float lf32 = (float)l;
    a   += l * (double)sw1[d * 256 + t];
    bb0 += lf32 * mw1[d * 512 + t];
    bb1 += lf32 * mw1[d * 512 + t + 256];
  }
  A1d[p * 256 + t] = a;
  B1[p * 512 + t]       = mb1[t]       + bb0;
  B1[p * 512 + t + 256] = mb1[t + 256] + bb1;
}

// ---------------------------------------------------------------- kernel B
// Spatial MLP in double: h1(256)->h2(128)->h3(3)->n_pos = tanh+pos.
// Writes pp (both halves) in double (for topk) and float (for downstream).
__global__ __launch_bounds__(256) void point_mlp(
    const float* __restrict__ pos, const float* __restrict__ sw1,
    const float* __restrict__ sw2, const float* __restrict__ sb2,
    const float* __restrict__ sw3, const float* __restrict__ sb3,
    const double* __restrict__ A1d, double* __restrict__ ppd, float* __restrict__ ppf) {
  __shared__ double h1[256];
  __shared__ double h2[128];
  __shared__ double posd[3];
  const int n = blockIdx.x, t = threadIdx.x;
  const int p = n >> 6, s = n & 63;
  if (t < 3) posd[t] = (double)pos[n * 3 + t];
  __syncthreads();
  double v = A1d[p * 256 + t];
  #pragma unroll
  for (int k = 0; k < 3; ++k) v += posd[k] * (double)sw1[(768 + k) * 256 + t];
  h1[t] = fmax(v, 0.0);
  __syncthreads();
  if (t < 128) {
    double u = (double)sb2[t];
    for (int k = 0; k < 256; ++k) u += h1[k] * (double)sw2[k * 128 + t];
    h2[t] = fmax(u, 0.0);
  }
  __syncthreads();
  if (t < 3) {
    double u = (double)sb3[t];
    for (int k = 0; k < 128; ++k) u += h2[k] * (double)sw3[k * 3 + t];
    u = fmax(u, 0.0);
    const double np_ = tanh(u) + posd[t];
    ppd[(p * 128 + 64 + s) * 3 + t] = np_;
    ppf[(p * 128 + 64 + s) * 3 + t] = (float)np_;
    ppd[(p * 128 + s) * 3 + t] = posd[t];
    ppf[(p * 128 + s) * 3 + t] = (float)posd[t];
  }
}

// ---------------------------------------------------------------- kernel C
// Per patch row i: 9 smallest d2 among 128 candidates with d2<=R2,
// evict lexicographic max (d2, idx) == jax top_k(-d2) set semantics.
__global__ __launch_bounds__(128) void neighbors_k(const double* __restrict__ ppd,
                                                   int* __restrict__ nbr) {
  __shared__ double X[128], Y[128], Z[128];
  const int p = blockIdx.x, i = threadIdx.x;
  X[i] = ppd[(p * 128 + i) * 3 + 0];
  Y[i] = ppd[(p * 128 + i) * 3 + 1];
  Z[i] = ppd[(p * 128 + i) * 3 + 2];
  __syncthreads();
  const double R2d = 0.3 * 0.3;
  const double xi = X[i], yi = Y[i], zi = Z[i];
  double bd[9];
  int bix[9];
  #pragma unroll
  for (int k = 0; k < 9; ++k) { bd[k] = 1e300; bix[k] = 1 << 29; }
  for (int j = 0; j < 128; ++j) {
    const double dx = X[j] - xi, dy = Y[j] - yi, dz = Z[j] - zi;
    const double d2 = dx * dx + dy * dy + dz * dz;
    double mx = bd[0]; int mi = bix[0], mk = 0;
    #pragma unroll
    for (int k = 1; k < 9; ++k) {
      const bool g = (bd[k] > mx) || (bd[k] == mx && bix[k] > mi);
      if (g) { mx = bd[k]; mi = bix[k]; mk = k; }
    }
    if (d2 <= R2d && d2 < mx) {
      #pragma unroll
      for (int k = 0; k < 9; ++k)
        if (k == mk) { bd[k] = d2; bix[k] = j; }
    }
  }
  #pragma unroll
  for (int k = 0; k < 9; ++k)
    nbr[(p * 128 + i) * 9 + k] = (bd[k] <= R2d) ? bix[k] : -1;
}

// ---------------------------------------------------------------- kernel D
// Edge MLP 6->64->128 per (point, neighbor), max-agg over <=9 neighbors.
// cw2 column lives in 64 VGPRs; m1 broadcast from LDS as float4.
__global__ __launch_bounds__(128) void edge_agg(
    const float* __restrict__ ppf, const int* __restrict__ nbr,
    const float* __restrict__ cw1, const float* __restrict__ cb1,
    const float* __restrict__ cw2, const float* __restrict__ cb2,
    float* __restrict__ agg) {
  __shared__ __align__(16) float m1[64];
  const int b = blockIdx.x;
  const int i = b & 127, p = b >> 7;
  const int t = threadIdx.x;
  float w[64];
  #pragma unroll
  for (int k = 0; k < 64; ++k) w[k] = cw2[k * 128 + t];
  const float cb2t = cb2[t];
  const int tt = t & 63;
  float c1w[6];
  #pragma unroll
  for (int q = 0; q < 6; ++q) c1w[q] = cw1[q * 64 + tt];
  const float c1b = cb1[tt];
  const float cx = ppf[(p * 128 + i) * 3 + 0];
  const float cy = ppf[(p * 128 + i) * 3 + 1];
  const float cz = ppf[(p * 128 + i) * 3 + 2];
  float acc = -1e30f;
  const int* nb = &nbr[(p * 128 + i) * 9];
  for (int k = 0; k < 9; ++k) {
    const int j = nb[k];  // block-uniform
    const bool valid = (j >= 0);
    if (valid && t < 64) {
      const float nx = ppf[(p * 128 + j) * 3 + 0];
      const float ny = ppf[(p * 128 + j) * 3 + 1];
      const float nz = ppf[(p * 128 + j) * 3 + 2];
      float v = c1b + nx * c1w[0] + ny * c1w[1] + nz * c1w[2] +
                (nx - cx) * c1w[3] + (ny - cy) * c1w[4] + (nz - cz) * c1w[5];
      m1[t] = fmaxf(v, 0.f);
    }
    __syncthreads();
    if (valid) {
      float v = cb2t;
      const float4* m4 = (const float4*)m1;
      #pragma unroll
      for (int q = 0; q < 16; ++q) {
        const float4 mm = m4[q];
        v += mm.x * w[4 * q] + mm.y * w[4 * q + 1] + mm.z * w[4 * q + 2] + mm.w * w[4 * q + 3];
      }
      acc = fmaxf(acc, fmaxf(v, 0.f));
    }
    __syncthreads();
  }
  agg[(p * 128 + i) * 128 + t] = acc;
}

// ---------------------------------------------------------------- kernel E
// Final MLP, 16 rows/block: g1(512) -> g2(256) -> g3(9)=rot -> rot^T rot.
// LDS: g1L [512][18] (stride-18: 2-way bank alias = free), aux reused for feaT/partials/g2L.
__global__ __launch_bounds__(256) void final_mlp(
    const float* __restrict__ agg, const float* __restrict__ B1,
    const float* __restrict__ mw1, const float* __restrict__ mw2,
    const float* __restrict__ mb2, const float* __restrict__ mw3,
    const float* __restrict__ mb3, float* __restrict__ rotw,
    float* __restrict__ out_rc) {
  __shared__ float smem[9216 + 4608 + 144];
  float* g1L = smem;            // [512][18]
  float* aux = smem + 9216;     // feaT [128][16] -> partials [128][32] -> g2L [256][18]
  float* rotL = smem + 9216 + 4608;  // [16][9]

  const int b = blockIdx.x, t = threadIdx.x;
  const int n0 = b * 16;
  int p, s0;
  if (n0 < NPTS) { p = n0 >> 6; s0 = n0 & 63; }
  else           { const int m = n0 - NPTS; p = m >> 6; s0 = 64 + (m & 63); }

  // stage 0: load fea tile transposed: feaT[k*16+r] = agg[(p*128+s0+r)*128+k]
  const float* ab = agg + (p * 128 + s0) * 128;
  for (int idx = t; idx < 2048; idx += 256) {
    const int r = idx >> 7, k = idx & 127;
    aux[k * 16 + r] = ab[idx];
  }
  __syncthreads();

  // stage 1: g1 = relu(B1 + fea @ mw1[768:896]); cols (t, t+256) x 16 rows
  {
    float acc0[16], acc1[16];
    const float bias0 = B1[p * 512 + t];
    const float bias1 = B1[p * 512 + t + 256];
    #pragma unroll
    for (int r = 0; r < 16; ++r) { acc0[r] = bias0; acc1[r] = bias1; }
    const float* w0p = mw1 + 768 * 512 + t;
    for (int k = 0; k < 128; ++k) {
      const float w0 = w0p[k * 512];
      const float w1 = w0p[k * 512 + 256];
      const float2* f2 = (const float2*)&aux[k * 16];
      #pragma unroll
      for (int q = 0; q < 8; ++q) {
        const float2 f = f2[q];
        acc0[2 * q]     += f.x * w0;  acc1[2 * q]     += f.x * w1;
        acc0[2 * q + 1] += f.y * w0;  acc1[2 * q + 1] += f.y * w1;
      }
    }
    __syncthreads();  // feaT dead only after ALL threads finish stage-1 loop
    #pragma unroll
    for (int r = 0; r < 16; ++r) {
      g1L[t * 18 + r]         = fmaxf(acc0[r], 0.f);
      g1L[(t + 256) * 18 + r] = fmaxf(acc1[r], 0.f);
    }
  }
  __syncthreads();

  // stage 2: g2 = relu(g1 @ mw2 + mb2); k split over two thread groups
  {
    const int c = t & 127, kh = t >> 7;
    float a0[16], a1[16];
    #pragma unroll
    for (int r = 0; r < 16; ++r) { a0[r] = 0.f; a1[r] = 0.f; }
    const float* w2p = mw2 + c;
    const int k0 = kh * 256;
    for (int k = k0; k < k0 + 256; ++k) {
      const float w0 = w2p[k * 256];
      const float w1 = w2p[k * 256 + 128];
      const float2* gg = (const float2*)&g1L[k * 18];
      #pragma unroll
      for (int q = 0; q < 8; ++q) {
        const float2 f = gg[q];
        a0[2 * q]     += f.x * w0;  a0[2 * q + 1] += f.y * w0;
        a1[2 * q]     += f.x * w1;  a1[2 * q + 1] += f.y * w1;
      }
    }
    if (kh) {
      #pragma unroll
      for (int r = 0; r < 16; ++r) { aux[c * 32 + r] = a0[r]; aux[c * 32 + 16 + r] = a1[r]; }
    }
    __syncthreads();
    if (!kh) {
      const float m0 = mb2[c], m1b = mb2[c + 128];
      #pragma unroll
      for (int r = 0; r < 16; ++r) {
        a0[r] = fmaxf(a0[r] + aux[c * 32 + r] + m0, 0.f);
        a1[r] = fmaxf(a1[r] + aux[c * 32 + 16 + r] + m1b, 0.f);
      }
    }
    __syncthreads();
    if (!kh) {
      #pragma unroll
      for (int r = 0; r < 16; ++r) {
        aux[c * 18 + r] = a0[r];            // g2L[k=c][r]
        aux[(c + 128) * 18 + r] = a1[r];
      }
    }
    __syncthreads();
  }

  // stage 3: g3/rot: 144 outputs (16 rows x 9)
  if (t < 144) {
    const int r = t / 9, jj = t % 9;
    float u = mb3[jj];
    for (int k = 0; k < 256; ++k) u += aux[k * 18 + r] * mw3[k * 9 + jj];
    u = fmaxf(u, 0.f);
    rotL[r * 9 + jj] = u;
    rotw[(n0 + r) * 9 + jj] = u;
  }
  __syncthreads();

  // stage 4: rot_constrain[n][i][j] = sum_k rot[k][i]*rot[k][j]
  if (t < 144) {
    const int r = t / 9, e = t % 9, ii = e / 3, jj2 = e % 3;
    const float* R = &rotL[r * 9];
    const float v = R[0 * 3 + ii] * R[0 * 3 + jj2] + R[1 * 3 + ii] * R[1 * 3 + jj2] +
                    R[2 * 3 + ii] * R[2 * 3 + jj2];
    out_rc[(n0 + r) * 9 + e] = v;
  }
}

// ---------------------------------------------------------------- kernel F
// plane_flat[q] = rot[q/16] @ npts[q%16] + pos_c[q % M]
__global__ __launch_bounds__(256) void plane_k(const float* __restrict__ rotw,
                                               const float* __restrict__ ppf,
                                               float* __restrict__ out_plane) {
  const int q = blockIdx.x * 256 + threadIdx.x;  // < 524288
  const int n = q >> 4, tt = q & 15;
  const float* R = &rotw[n * 9];
  const int tx = tt & 3, ty = tt >> 2;
  const double step = 0.4 / 3.0;  // matches np.linspace arithmetic
  const float X = (tx == 3) ? 0.2f : (float)((double)tx * step - 0.2);
  const float Y = (ty == 3) ? 0.2f : (float)((double)ty * step - 0.2);
  const int m = q & (M2N - 1);  // q mod 32768
  int p, s;
  if (m < NPTS) { p = m >> 6; s = m & 63; }
  else          { const int mm = m - NPTS; p = mm >> 6; s = 64 + (mm & 63); }
  const float* C = &ppf[(p * 128 + s) * 3];
  #pragma unroll
  for (int i2 = 0; i2 < 3; ++i2) {
    const float d = R[i2 * 3 + 0] * X + R[i2 * 3 + 1] * Y;  // npts z == 0
    out_plane[q * 3 + i2] = d + C[i2];
  }
}

// ---------------------------------------------------------------- launch
extern "C" void kernel_launch(void* const* d_in, const int* in_sizes, int n_in,
                              void* d_out, int out_size, void* d_ws, size_t ws_size,
                              hipStream_t stream) {
  const float* pos       = (const float*)d_in[1];
  const float* local_fea = (const float*)d_in[4];
  const float* sw1 = (const float*)d_in[5];
  const float* sb1 = (const float*)d_in[6];
  const float* sw2 = (const float*)d_in[7];
  const float* sb2 = (const float*)d_in[8];
  const float* sw3 = (const float*)d_in[9];
  const float* sb3 = (const float*)d_in[10];
  const float* cw1 = (const float*)d_in[11];
  const float* cb1 = (const float*)d_in[12];
  const float* cw2 = (const float*)d_in[13];
  const float* cb2 = (const float*)d_in[14];
  const float* mw1 = (const float*)d_in[15];
  const float* mb1 = (const float*)d_in[16];
  const float* mw2 = (const float*)d_in[17];
  const float* mb2 = (const float*)d_in[18];
  const float* mw3 = (const float*)d_in[19];
  const float* mb3 = (const float*)d_in[20];

  char* ws = (char*)d_ws;
  double* A1d = (double*)(ws + 0);         // 256*256*8   = 524288
  double* ppd = (double*)(ws + 524288);    // 256*128*3*8 = 786432
  float*  B1  = (float*)(ws + 1310720);    // 256*512*4   = 524288
  float*  ppf = (float*)(ws + 1835008);    // 256*128*3*4 = 393216
  int*    nbr = (int*)(ws + 2228224);      // 32768*9*4   = 1179648
  float*  agg = (float*)(ws + 3407872);    // 32768*128*4 = 16777216
  float*  rotw = (float*)(ws + 20185088);  // 32768*9*4   = 1179648  (end 21364736)

  float* out_plane = (float*)d_out;
  float* out_rc = out_plane + 1572864;  // P*2048*3

  patch_pre<<<256, 256, 0, stream>>>(local_fea, sw1, sb1, mw1, mb1, A1d, B1);
  point_mlp<<<16384, 256, 0, stream>>>(pos, sw1, sw2, sb2, sw3, sb3, A1d, ppd, ppf);
  neighbors_k<<<256, 128, 0, stream>>>(ppd, nbr);
  edge_agg<<<32768, 128, 0, stream>>>(ppf, nbr, cw1, cb1, cw2, cb2, agg);
  final_mlp<<<2048, 256, 0, stream>>>(agg, B1, mw1, mw2, mb2, mw3, mb3, rotw, out_rc);
  plane_k<<<2048, 256, 0, stream>>>(rotw, ppf, out_plane);
}

// Round 3
// 458.386 us; speedup vs baseline: 1.5311x; 1.5311x over previous
//
#include <hip/hip_runtime.h>

// PlanePriorNet: P=256 patches x PT=64 pts, D=768. float32 I/O.
// Round 3: final_mlp -> bf16 MFMA (16x16x32), weights pre-packed into B-fragment
// order, activations staged in LDS (row pitch = +16B => 2-way bank alias, free).
// fp64 kept on the chain feeding the discrete top-k.

#define P 256
#define PT 64
#define NPTS 16384          // P*PT
#define M2N 32768           // 2*N
#define D 768

typedef __attribute__((ext_vector_type(8))) short bfrag;   // 8 x bf16 (4 VGPR)
typedef __attribute__((ext_vector_type(4))) float ffrag;   // 4 x f32 acc

#define MFMA16(a, b, c) __builtin_amdgcn_mfma_f32_16x16x32_bf16((a), (b), (c), 0, 0, 0)

// round-to-nearest-even fp32 -> bf16
__device__ __forceinline__ ushort f2bf(float x) {
  unsigned u = __float_as_uint(x);
  u = (u + 0x7FFFu + ((u >> 16) & 1u)) >> 16;
  return (ushort)u;
}

// ---------------------------------------------------------------- kernel A
// A1d[p][c] = sb1[c] + sum_d lf[p][d]*sw1[d][c]          (double, c<256)
// B1 [p][c] = mb1[c] + sum_d lf[p][d]*mw1[d][c]          (float,  c<512)
__global__ __launch_bounds__(256) void patch_pre(
    const float* __restrict__ lf, const float* __restrict__ sw1,
    const float* __restrict__ sb1, const float* __restrict__ mw1,
    const float* __restrict__ mb1, double* __restrict__ A1d, float* __restrict__ B1) {
  __shared__ double lfs[768];
  const int p = blockIdx.x, t = threadIdx.x;
  for (int i = t; i < 768; i += 256) lfs[i] = (double)lf[p * 768 + i];
  __syncthreads();
  double a = (double)sb1[t];
  float bb0 = 0.f, bb1 = 0.f;
  for (int d = 0; d < 768; ++d) {
    const double l = lfs[d];
    const float lf32 = (float)l;
    a   += l * (double)sw1[d * 256 + t];
    bb0 += lf32 * mw1[d * 512 + t];
    bb1 += lf32 * mw1[d * 512 + t + 256];
  }
  A1d[p * 256 + t] = a;
  B1[p * 512 + t]       = mb1[t]       + bb0;
  B1[p * 512 + t + 256] = mb1[t + 256] + bb1;
}

// ---------------------------------------------------------------- kernel B
// Spatial MLP in double: h1(256)->h2(128)->h3(3)->n_pos = tanh+pos.
__global__ __launch_bounds__(256) void point_mlp(
    const float* __restrict__ pos, const float* __restrict__ sw1,
    const float* __restrict__ sw2, const float* __restrict__ sb2,
    const float* __restrict__ sw3, const float* __restrict__ sb3,
    const double* __restrict__ A1d, double* __restrict__ ppd, float* __restrict__ ppf) {
  __shared__ double h1[256];
  __shared__ double h2[128];
  __shared__ double posd[3];
  const int n = blockIdx.x, t = threadIdx.x;
  const int p = n >> 6, s = n & 63;
  if (t < 3) posd[t] = (double)pos[n * 3 + t];
  __syncthreads();
  double v = A1d[p * 256 + t];
  #pragma unroll
  for (int k = 0; k < 3; ++k) v += posd[k] * (double)sw1[(768 + k) * 256 + t];
  h1[t] = fmax(v, 0.0);
  __syncthreads();
  if (t < 128) {
    double u = (double)sb2[t];
    for (int k = 0; k < 256; ++k) u += h1[k] * (double)sw2[k * 128 + t];
    h2[t] = fmax(u, 0.0);
  }
  __syncthreads();
  if (t < 3) {
    double u = (double)sb3[t];
    for (int k = 0; k < 128; ++k) u += h2[k] * (double)sw3[k * 3 + t];
    u = fmax(u, 0.0);
    const double np_ = tanh(u) + posd[t];
    ppd[(p * 128 + 64 + s) * 3 + t] = np_;
    ppf[(p * 128 + 64 + s) * 3 + t] = (float)np_;
    ppd[(p * 128 + s) * 3 + t] = posd[t];
    ppf[(p * 128 + s) * 3 + t] = (float)posd[t];
  }
}

// ---------------------------------------------------------------- kernel C
// Per patch row i: 9 smallest d2 among 128 candidates with d2<=R2,
// evict lexicographic max (d2, idx) == jax top_k(-d2) set semantics.
__global__ __launch_bounds__(128) void neighbors_k(const double* __restrict__ ppd,
                                                   int* __restrict__ nbr) {
  __shared__ double X[128], Y[128], Z[128];
  const int p = blockIdx.x, i = threadIdx.x;
  X[i] = ppd[(p * 128 + i) * 3 + 0];
  Y[i] = ppd[(p * 128 + i) * 3 + 1];
  Z[i] = ppd[(p * 128 + i) * 3 + 2];
  __syncthreads();
  const double R2d = 0.3 * 0.3;
  const double xi = X[i], yi = Y[i], zi = Z[i];
  double bd[9];
  int bix[9];
  #pragma unroll
  for (int k = 0; k < 9; ++k) { bd[k] = 1e300; bix[k] = 1 << 29; }
  for (int j = 0; j < 128; ++j) {
    const double dx = X[j] - xi, dy = Y[j] - yi, dz = Z[j] - zi;
    const double d2 = dx * dx + dy * dy + dz * dz;
    double mx = bd[0]; int mi = bix[0], mk = 0;
    #pragma unroll
    for (int k = 1; k < 9; ++k) {
      const bool g = (bd[k] > mx) || (bd[k] == mx && bix[k] > mi);
      if (g) { mx = bd[k]; mi = bix[k]; mk = k; }
    }
    if (d2 <= R2d && d2 < mx) {
      #pragma unroll
      for (int k = 0; k < 9; ++k)
        if (k == mk) { bd[k] = d2; bix[k] = j; }
    }
  }
  #pragma unroll
  for (int k = 0; k < 9; ++k)
    nbr[(p * 128 + i) * 9 + k] = (bd[k] <= R2d) ? bix[k] : -1;
}

// ---------------------------------------------------------------- kernel D
// Edge MLP 6->64->128 per (point, neighbor), max-agg over <=9 neighbors.
__global__ __launch_bounds__(128) void edge_agg(
    const float* __restrict__ ppf, const int* __restrict__ nbr,
    const float* __restrict__ cw1, const float* __restrict__ cb1,
    const float* __restrict__ cw2, const float* __restrict__ cb2,
    float* __restrict__ agg) {
  __shared__ __align__(16) float m1[64];
  const int b = blockIdx.x;
  const int i = b & 127, p = b >> 7;
  const int t = threadIdx.x;
  float w[64];
  #pragma unroll
  for (int k = 0; k < 64; ++k) w[k] = cw2[k * 128 + t];
  const float cb2t = cb2[t];
  const int tt = t & 63;
  float c1w[6];
  #pragma unroll
  for (int q = 0; q < 6; ++q) c1w[q] = cw1[q * 64 + tt];
  const float c1b = cb1[tt];
  const float cx = ppf[(p * 128 + i) * 3 + 0];
  const float cy = ppf[(p * 128 + i) * 3 + 1];
  const float cz = ppf[(p * 128 + i) * 3 + 2];
  float acc = -1e30f;
  const int* nb = &nbr[(p * 128 + i) * 9];
  for (int k = 0; k < 9; ++k) {
    const int j = nb[k];  // block-uniform
    const bool valid = (j >= 0);
    if (valid && t < 64) {
      const float nx = ppf[(p * 128 + j) * 3 + 0];
      const float ny = ppf[(p * 128 + j) * 3 + 1];
      const float nz = ppf[(p * 128 + j) * 3 + 2];
      float v = c1b + nx * c1w[0] + ny * c1w[1] + nz * c1w[2] +
                (nx - cx) * c1w[3] + (ny - cy) * c1w[4] + (nz - cz) * c1w[5];
      m1[t] = fmaxf(v, 0.f);
    }
    __syncthreads();
    if (valid) {
      float v = cb2t;
      const float4* m4 = (const float4*)m1;
      #pragma unroll
      for (int q = 0; q < 16; ++q) {
        const float4 mm = m4[q];
        v += mm.x * w[4 * q] + mm.y * w[4 * q + 1] + mm.z * w[4 * q + 2] + mm.w * w[4 * q + 3];
      }
      acc = fmaxf(acc, fmaxf(v, 0.f));
    }
    __syncthreads();
  }
  agg[(p * 128 + i) * 128 + t] = acc;
}

// ---------------------------------------------------------------- kernel W
// Pack mw1[768:896], mw2, mw3(pad N->16) into MFMA B-fragment order:
// dst[((nt*KT + kt)*64 + lane)*8 + j] = W[kt*32 + (lane>>4)*8 + j][nt*16 + (lane&15)]
__global__ __launch_bounds__(256) void prepack_w(
    const float* __restrict__ mw1, const float* __restrict__ mw2,
    const float* __restrict__ mw3, ushort* __restrict__ W1p,
    ushort* __restrict__ W2p, ushort* __restrict__ W3p) {
  const int idx = blockIdx.x * 256 + threadIdx.x;
  if (idx < 65536) {                       // W1p: K=128 (kt<4), N=512 (nt<32)
    const int j = idx & 7, l = (idx >> 3) & 63, kt = (idx >> 9) & 3, nt = idx >> 11;
    const int k = kt * 32 + (l >> 4) * 8 + j, n = nt * 16 + (l & 15);
    W1p[idx] = f2bf(mw1[(768 + k) * 512 + n]);
  } else if (idx < 65536 + 131072) {       // W2p: K=512 (kt<16), N=256 (nt<16)
    const int q = idx - 65536;
    const int j = q & 7, l = (q >> 3) & 63, kt = (q >> 9) & 15, nt = q >> 13;
    const int k = kt * 32 + (l >> 4) * 8 + j, n = nt * 16 + (l & 15);
    W2p[q] = f2bf(mw2[k * 256 + n]);
  } else if (idx < 200704) {               // W3p: K=256 (kt<8), N=9 padded to 16
    const int q = idx - 196608;
    const int j = q & 7, l = (q >> 3) & 63, kt = q >> 9;
    const int k = kt * 32 + (l >> 4) * 8 + j, n = l & 15;
    W3p[q] = (n < 9) ? f2bf(mw3[k * 9 + n]) : (ushort)0;
  }
}

// ---------------------------------------------------------------- kernel E
// Final MLP via MFMA: 32 rows/block, 1024 blocks.
// g1 = relu(fea[32x128] @ W1 + B1[p])  -> LDS bf16
// g2 = relu(g1 @ W2 + mb2)             -> LDS bf16
// g3 = relu(g2 @ W3 + mb3) = rot       -> rotw + rot_constrain
#define PA  136   // aT pitch (bf16 elems): 272 B row stride, == 16 mod 128 B
#define PG1 520   // 1040 B
#define PG2 264   // 528 B
__global__ __launch_bounds__(256) void final_mlp_mfma(
    const float* __restrict__ agg, const float* __restrict__ B1,
    const ushort* __restrict__ W1p, const ushort* __restrict__ W2p,
    const ushort* __restrict__ W3p, const float* __restrict__ mb2,
    const float* __restrict__ mb3, float* __restrict__ rotw,
    float* __restrict__ out_rc) {
  __shared__ __align__(16) ushort g1T[32 * PG1];   // 33280 B
  __shared__ __align__(16) ushort reg2[32 * PG2];  // 16896 B: aT (stage0/1) then g2T
  __shared__ float rotL[32 * 9];                   // 1152 B
  const int b = blockIdx.x, t = threadIdx.x;
  const int w = t >> 6, l = t & 63;
  const int lrow = l & 15, quad = l >> 4;
  int p, off;
  if (b < 512) { p = b >> 1;         off = (b & 1) * 32; }
  else         { p = (b - 512) >> 1; off = 64 + ((b - 512) & 1) * 32; }
  const int n0 = b * 32;  // global output row base (works for both halves)

  // ---- stage 0: agg tile (fp32) -> bf16 -> LDS aT[32][128] pitch PA
  {
    ushort* aT = reg2;
    const int r0 = t >> 3, sg = (t & 7) * 16;
    const float4* src = (const float4*)(agg + (size_t)(p * 128 + off + r0) * 128 + sg);
    union { ushort us[16]; uint4 u4[2]; } tmp;
    #pragma unroll
    for (int q = 0; q < 4; ++q) {
      const float4 v = src[q];
      tmp.us[4 * q + 0] = f2bf(v.x); tmp.us[4 * q + 1] = f2bf(v.y);
      tmp.us[4 * q + 2] = f2bf(v.z); tmp.us[4 * q + 3] = f2bf(v.w);
    }
    uint4* dst = (uint4*)&aT[r0 * PA + sg];
    dst[0] = tmp.u4[0]; dst[1] = tmp.u4[1];
  }
  __syncthreads();

  // ---- stage 1: g1 (M=32, N=512, K=128); wave w covers N cols [w*128, w*128+128)
  {
    const ushort* aT = reg2;
    bfrag a[2][4];
    #pragma unroll
    for (int mt = 0; mt < 2; ++mt)
      #pragma unroll
      for (int kt = 0; kt < 4; ++kt)
        a[mt][kt] = *(const bfrag*)&aT[(mt * 16 + lrow) * PA + kt * 32 + quad * 8];
    ffrag acc[2][8];
    #pragma unroll
    for (int nti = 0; nti < 8; ++nti) {
      const float bv = B1[p * 512 + (w * 8 + nti) * 16 + lrow];
      acc[0][nti] = (ffrag){bv, bv, bv, bv};
      acc[1][nti] = acc[0][nti];
    }
    #pragma unroll
    for (int nti = 0; nti < 8; ++nti) {
      const int nt = w * 8 + nti;
      #pragma unroll
      for (int kt = 0; kt < 4; ++kt) {
        const bfrag bb = *(const bfrag*)&W1p[((nt * 4 + kt) * 64 + l) * 8];
        acc[0][nti] = MFMA16(a[0][kt], bb, acc[0][nti]);
        acc[1][nti] = MFMA16(a[1][kt], bb, acc[1][nti]);
      }
    }
    #pragma unroll
    for (int mt = 0; mt < 2; ++mt)
      #pragma unroll
      for (int nti = 0; nti < 8; ++nti) {
        const int col = (w * 8 + nti) * 16 + lrow;
        #pragma unroll
        for (int r = 0; r < 4; ++r)
          g1T[(mt * 16 + quad * 4 + r) * PG1 + col] = f2bf(fmaxf(acc[mt][nti][r], 0.f));
      }
  }
  __syncthreads();

  // ---- stage 2: g2 (M=32, N=256, K=512); wave w covers N cols [w*64, w*64+64)
  {
    bfrag a[2][16];
    #pragma unroll
    for (int mt = 0; mt < 2; ++mt)
      #pragma unroll
      for (int kt = 0; kt < 16; ++kt)
        a[mt][kt] = *(const bfrag*)&g1T[(mt * 16 + lrow) * PG1 + kt * 32 + quad * 8];
    ffrag acc[2][4];
    #pragma unroll
    for (int nti = 0; nti < 4; ++nti) {
      acc[0][nti] = (ffrag){0.f, 0.f, 0.f, 0.f};
      acc[1][nti] = acc[0][nti];
    }
    #pragma unroll
    for (int nti = 0; nti < 4; ++nti) {
      const int nt = w * 4 + nti;
      #pragma unroll
      for (int kt = 0; kt < 16; ++kt) {
        const bfrag bb = *(const bfrag*)&W2p[((nt * 16 + kt) * 64 + l) * 8];
        acc[0][nti] = MFMA16(a[0][kt], bb, acc[0][nti]);
        acc[1][nti] = MFMA16(a[1][kt], bb, acc[1][nti]);
      }
    }
    ushort* g2T = reg2;  // all aT reads finished before the post-stage-1 barrier
    #pragma unroll
    for (int mt = 0; mt < 2; ++mt)
      #pragma unroll
      for (int nti = 0; nti < 4; ++nti) {
        const int col = (w * 4 + nti) * 16 + lrow;
        const float bv = mb2[col];
        #pragma unroll
        for (int r = 0; r < 4; ++r)
          g2T[(mt * 16 + quad * 4 + r) * PG2 + col] =
              f2bf(fmaxf(acc[mt][nti][r] + bv, 0.f));
      }
  }
  __syncthreads();

  // ---- stage 3: g3 (M=32, N=16 padded, K=256); waves 0,1 take mt=w
  if (w < 2) {
    const ushort* g2T = reg2;
    ffrag acc = (ffrag){0.f, 0.f, 0.f, 0.f};
    #pragma unroll
    for (int kt = 0; kt < 8; ++kt) {
      const bfrag aa = *(const bfrag*)&g2T[(w * 16 + lrow) * PG2 + kt * 32 + quad * 8];
      const bfrag bb = *(const bfrag*)&W3p[(kt * 64 + l) * 8];
      acc = MFMA16(aa, bb, acc);
    }
    if (lrow < 9) {
      const float bv = mb3[lrow];
      #pragma unroll
      for (int r = 0; r < 4; ++r) {
        const int m = w * 16 + quad * 4 + r;
        const float u = fmaxf(acc[r] + bv, 0.f);
        rotL[m * 9 + lrow] = u;
        rotw[(size_t)(n0 + m) * 9 + lrow] = u;
      }
    }
  }
  __syncthreads();

  // ---- stage 4: rot_constrain[i][j] = sum_k rot[k][i]*rot[k][j]
  for (int idx = t; idx < 288; idx += 256) {
    const int r = idx / 9, e = idx % 9, ii = e / 3, jj = e % 3;
    const float* R = &rotL[r * 9];
    out_rc[(size_t)(n0 + r) * 9 + e] =
        R[ii] * R[jj] + R[3 + ii] * R[3 + jj] + R[6 + ii] * R[6 + jj];
  }
}

// ---------------------------------------------------------------- kernel F
// plane_flat[q] = rot[q/16] @ npts[q%16] + pos_c[q % M]
__global__ __launch_bounds__(256) void plane_k(const float* __restrict__ rotw,
                                               const float* __restrict__ ppf,
                                               float* __restrict__ out_plane) {
  const int q = blockIdx.x * 256 + threadIdx.x;  // < 524288
  const int n = q >> 4, tt = q & 15;
  const float* R = &rotw[n * 9];
  const int tx = tt & 3, ty = tt >> 2;
  const double step = 0.4 / 3.0;  // matches np.linspace arithmetic
  const float X = (tx == 3) ? 0.2f : (float)((double)tx * step - 0.2);
  const float Y = (ty == 3) ? 0.2f : (float)((double)ty * step - 0.2);
  const int m = q & (M2N - 1);  // q mod 32768
  int p, s;
  if (m < NPTS) { p = m >> 6; s = m & 63; }
  else          { const int mm = m - NPTS; p = mm >> 6; s = 64 + (mm & 63); }
  const float* C = &ppf[(p * 128 + s) * 3];
  #pragma unroll
  for (int i2 = 0; i2 < 3; ++i2) {
    const float d = R[i2 * 3 + 0] * X + R[i2 * 3 + 1] * Y;  // npts z == 0
    out_plane[q * 3 + i2] = d + C[i2];
  }
}

// ---------------------------------------------------------------- launch
extern "C" void kernel_launch(void* const* d_in, const int* in_sizes, int n_in,
                              void* d_out, int out_size, void* d_ws, size_t ws_size,
                              hipStream_t stream) {
  const float* pos       = (const float*)d_in[1];
  const float* local_fea = (const float*)d_in[4];
  const float* sw1 = (const float*)d_in[5];
  const float* sb1 = (const float*)d_in[6];
  const float* sw2 = (const float*)d_in[7];
  const float* sb2 = (const float*)d_in[8];
  const float* sw3 = (const float*)d_in[9];
  const float* sb3 = (const float*)d_in[10];
  const float* cw1 = (const float*)d_in[11];
  const float* cb1 = (const float*)d_in[12];
  const float* cw2 = (const float*)d_in[13];
  const float* cb2 = (const float*)d_in[14];
  const float* mw1 = (const float*)d_in[15];
  const float* mb1 = (const float*)d_in[16];
  const float* mw2 = (const float*)d_in[17];
  const float* mb2 = (const float*)d_in[18];
  const float* mw3 = (const float*)d_in[19];
  const float* mb3 = (const float*)d_in[20];

  char* ws = (char*)d_ws;
  double* A1d = (double*)(ws + 0);         // 256*256*8   = 524288
  double* ppd = (double*)(ws + 524288);    // 256*128*3*8 = 786432
  float*  B1  = (float*)(ws + 1310720);    // 256*512*4   = 524288
  float*  ppf = (float*)(ws + 1835008);    // 256*128*3*4 = 393216
  int*    nbr = (int*)(ws + 2228224);      // 32768*9*4   = 1179648
  float*  agg = (float*)(ws + 3407872);    // 32768*128*4 = 16777216
  float*  rotw = (float*)(ws + 20185088);  // 32768*9*4   = 1179648
  ushort* W1p = (ushort*)(ws + 21364736);  // 65536*2     = 131072
  ushort* W2p = (ushort*)(ws + 21495808);  // 131072*2    = 262144
  ushort* W3p = (ushort*)(ws + 21757952);  // 4096*2      = 8192   (end 21766144)

  float* out_plane = (float*)d_out;
  float* out_rc = out_plane + 1572864;  // P*2048*3

  patch_pre<<<256, 256, 0, stream>>>(local_fea, sw1, sb1, mw1, mb1, A1d, B1);
  point_mlp<<<16384, 256, 0, stream>>>(pos, sw1, sw2, sb2, sw3, sb3, A1d, ppd, ppf);
  neighbors_k<<<256, 128, 0, stream>>>(ppd, nbr);
  prepack_w<<<784, 256, 0, stream>>>(mw1, mw2, mw3, W1p, W2p, W3p);
  edge_agg<<<32768, 128, 0, stream>>>(ppf, nbr, cw1, cb1, cw2, cb2, agg);
  final_mlp_mfma<<<1024, 256, 0, stream>>>(agg, B1, W1p, W2p, W3p, mb2, mb3, rotw, out_rc);
  plane_k<<<2048, 256, 0, stream>>>(rotw, ppf, out_plane);
}

// Round 4
// 387.819 us; speedup vs baseline: 1.8097x; 1.1820x over previous
//
#include <hip/hip_runtime.h>

// PlanePriorNet: P=256 patches x PT=64 pts, D=768. float32 I/O.
// Round 4: point_mlp -> patch-level fp64 register GEMM (1 block/patch);
//          edge MLP -> bf16x3 MFMA (m2), agg stored bf16.
// fp64 kept on the chain feeding the discrete top-k.

#define P 256
#define PT 64
#define NPTS 16384          // P*PT
#define M2N 32768           // 2*N
#define D 768

typedef __attribute__((ext_vector_type(8))) short bfrag;   // 8 x bf16 (4 VGPR)
typedef __attribute__((ext_vector_type(4))) float ffrag;   // 4 x f32 acc

#define MFMA16(a, b, c) __builtin_amdgcn_mfma_f32_16x16x32_bf16((a), (b), (c), 0, 0, 0)

// round-to-nearest-even fp32 -> bf16
__device__ __forceinline__ ushort f2bf(float x) {
  unsigned u = __float_as_uint(x);
  u = (u + 0x7FFFu + ((u >> 16) & 1u)) >> 16;
  return (ushort)u;
}
__device__ __forceinline__ float bf2f(ushort u) {
  return __uint_as_float((unsigned)u << 16);
}

// ---------------------------------------------------------------- kernel A
// A1d[p][c] = sb1[c] + sum_d lf[p][d]*sw1[d][c]          (double, c<256)
// B1 [p][c] = mb1[c] + sum_d lf[p][d]*mw1[d][c]          (float,  c<512)
__global__ __launch_bounds__(256) void patch_pre(
    const float* __restrict__ lf, const float* __restrict__ sw1,
    const float* __restrict__ sb1, const float* __restrict__ mw1,
    const float* __restrict__ mb1, double* __restrict__ A1d, float* __restrict__ B1) {
  __shared__ double lfs[768];
  const int p = blockIdx.x, t = threadIdx.x;
  for (int i = t; i < 768; i += 256) lfs[i] = (double)lf[p * 768 + i];
  __syncthreads();
  double a = (double)sb1[t];
  float bb0 = 0.f, bb1 = 0.f;
  for (int d = 0; d < 768; ++d) {
    const double l = lfs[d];
    const float lf32 = (float)l;
    a   += l * (double)sw1[d * 256 + t];
    bb0 += lf32 * mw1[d * 512 + t];
    bb1 += lf32 * mw1[d * 512 + t + 256];
  }
  A1d[p * 256 + t] = a;
  B1[p * 512 + t]       = mb1[t]       + bb0;
  B1[p * 512 + t + 256] = mb1[t + 256] + bb1;
}

// ---------------------------------------------------------------- kernel B
// Spatial MLP in fp64, one block per patch (64 pts), two half-batches of 32.
// h1T[k][pt] in LDS; stage2: thread=(col,grp) accumulates 16 pts per weight load.
__global__ __launch_bounds__(256) void point_mlp2(
    const float* __restrict__ pos, const float* __restrict__ sw1,
    const float* __restrict__ sw2, const float* __restrict__ sb2,
    const float* __restrict__ sw3, const float* __restrict__ sb3,
    const double* __restrict__ A1d, double* __restrict__ ppd, float* __restrict__ ppf) {
  __shared__ double h1T[256 * 33];   // [k][pt], pitch 33 (67584 B)
  __shared__ double h2s[32 * 129];   // [pt][c], pitch 129 (33024 B)
  __shared__ double posd[64 * 3];
  const int p = blockIdx.x, t = threadIdx.x;
  const double a1 = A1d[p * 256 + t];
  const double w0 = (double)sw1[768 * 256 + t];
  const double w1 = (double)sw1[769 * 256 + t];
  const double w2 = (double)sw1[770 * 256 + t];
  for (int i = t; i < 192; i += 256) posd[i] = (double)pos[p * 192 + i];
  __syncthreads();
  for (int half = 0; half < 2; ++half) {
    const int hbase = half * 32;
    // stage 1: h1T[t][r] = relu(a1 + pos . sw1r)  (thread t = k)
    for (int r = 0; r < 32; ++r) {
      const double* pp = &posd[(hbase + r) * 3];
      const double v = a1 + pp[0] * w0 + pp[1] * w1 + pp[2] * w2;
      h1T[t * 33 + r] = v > 0.0 ? v : 0.0;
    }
    __syncthreads();
    // stage 2: h2[pt][c] = relu(sb2 + sum_k h1[pt][k]*sw2[k][c])
    {
      const int c = t & 127, grp = t >> 7;
      const double sb2d = (double)sb2[c];
      double acc[16];
      #pragma unroll
      for (int r = 0; r < 16; ++r) acc[r] = 0.0;
      for (int k = 0; k < 256; ++k) {
        const double w = (double)sw2[k * 128 + c];
        const double* hrow = &h1T[k * 33 + grp * 16];  // broadcast reads
        #pragma unroll
        for (int r = 0; r < 16; ++r) acc[r] += hrow[r] * w;
      }
      const int pb = grp * 16;
      #pragma unroll
      for (int r = 0; r < 16; ++r) {
        const double u = acc[r] + sb2d;
        h2s[(pb + r) * 129 + c] = u > 0.0 ? u : 0.0;
      }
    }
    __syncthreads();
    // stage 3: h3 + tanh + writes (96 threads: 32 pts x 3 coords)
    if (t < 96) {
      const int r = t / 3, j = t % 3;
      double u = (double)sb3[j];
      #pragma unroll 4
      for (int c = 0; c < 128; ++c)
        u += h2s[r * 129 + c] * (double)sw3[c * 3 + j];
      u = u > 0.0 ? u : 0.0;
      const int s = hbase + r;
      const double po = posd[s * 3 + j];
      const double np_ = tanh(u) + po;
      const size_t rn = (size_t)(p * 128 + 64 + s) * 3 + j;
      const size_t ro = (size_t)(p * 128 + s) * 3 + j;
      ppd[rn] = np_;  ppf[rn] = (float)np_;
      ppd[ro] = po;   ppf[ro] = (float)po;
    }
    __syncthreads();
  }
}

// ---------------------------------------------------------------- kernel C
// Per patch row i: 9 smallest d2 among 128 candidates with d2<=R2,
// evict lexicographic max (d2, idx) == jax top_k(-d2) set semantics.
__global__ __launch_bounds__(128) void neighbors_k(const double* __restrict__ ppd,
                                                   int* __restrict__ nbr) {
  __shared__ double X[128], Y[128], Z[128];
  const int p = blockIdx.x, i = threadIdx.x;
  X[i] = ppd[(p * 128 + i) * 3 + 0];
  Y[i] = ppd[(p * 128 + i) * 3 + 1];
  Z[i] = ppd[(p * 128 + i) * 3 + 2];
  __syncthreads();
  const double R2d = 0.3 * 0.3;
  const double xi = X[i], yi = Y[i], zi = Z[i];
  double bd[9];
  int bix[9];
  #pragma unroll
  for (int k = 0; k < 9; ++k) { bd[k] = 1e300; bix[k] = 1 << 29; }
  for (int j = 0; j < 128; ++j) {
    const double dx = X[j] - xi, dy = Y[j] - yi, dz = Z[j] - zi;
    const double d2 = dx * dx + dy * dy + dz * dz;
    double mx = bd[0]; int mi = bix[0], mk = 0;
    #pragma unroll
    for (int k = 1; k < 9; ++k) {
      const bool g = (bd[k] > mx) || (bd[k] == mx && bix[k] > mi);
      if (g) { mx = bd[k]; mi = bix[k]; mk = k; }
    }
    if (d2 <= R2d && d2 < mx) {
      #pragma unroll
      for (int k = 0; k < 9; ++k)
        if (k == mk) { bd[k] = d2; bix[k] = j; }
    }
  }
  #pragma unroll
  for (int k = 0; k < 9; ++k)
    nbr[(p * 128 + i) * 9 + k] = (bd[k] <= R2d) ? bix[k] : -1;
}

// ---------------------------------------------------------------- kernel W
// Pack mw1[768:896], mw2, mw3(pad N->16), cw2(hi/lo) into MFMA B-fragment order:
// dst[((nt*KT + kt)*64 + lane)*8 + j] = W[kt*32 + (lane>>4)*8 + j][nt*16 + (lane&15)]
__global__ __launch_bounds__(256) void prepack_w(
    const float* __restrict__ mw1, const float* __restrict__ mw2,
    const float* __restrict__ mw3, const float* __restrict__ cw2,
    ushort* __restrict__ W1p, ushort* __restrict__ W2p, ushort* __restrict__ W3p,
    ushort* __restrict__ C2h, ushort* __restrict__ C2l) {
  const int idx = blockIdx.x * 256 + threadIdx.x;
  if (idx < 65536) {                       // W1p: K=128 (kt<4), N=512 (nt<32)
    const int j = idx & 7, l = (idx >> 3) & 63, kt = (idx >> 9) & 3, nt = idx >> 11;
    const int k = kt * 32 + (l >> 4) * 8 + j, n = nt * 16 + (l & 15);
    W1p[idx] = f2bf(mw1[(768 + k) * 512 + n]);
  } else if (idx < 196608) {               // W2p: K=512 (kt<16), N=256 (nt<16)
    const int q = idx - 65536;
    const int j = q & 7, l = (q >> 3) & 63, kt = (q >> 9) & 15, nt = q >> 13;
    const int k = kt * 32 + (l >> 4) * 8 + j, n = nt * 16 + (l & 15);
    W2p[q] = f2bf(mw2[k * 256 + n]);
  } else if (idx < 200704) {               // W3p: K=256 (kt<8), N=9 padded to 16
    const int q = idx - 196608;
    const int j = q & 7, l = (q >> 3) & 63, kt = q >> 9;
    const int k = kt * 32 + (l >> 4) * 8 + j, n = l & 15;
    W3p[q] = (n < 9) ? f2bf(mw3[k * 9 + n]) : (ushort)0;
  } else if (idx < 208896) {               // C2h/C2l: K=64 (kt<2), N=128 (nt<8)
    const int q = idx - 200704;
    const int j = q & 7, l = (q >> 3) & 63, kt = (q >> 9) & 1, nt = q >> 10;
    const int k = kt * 32 + (l >> 4) * 8 + j, n = nt * 16 + (l & 15);
    const float v = cw2[k * 128 + n];
    const ushort hi = f2bf(v);
    C2h[q] = hi;
    C2l[q] = f2bf(v - bf2f(hi));
  }
}

// ---------------------------------------------------------------- kernel D
// Edge MLP via MFMA: 16 pts/block (144 edges, M-tiles=9), N=128, K=64.
// m1 (K=6) on VALU -> LDS bf16 hi/lo; m2 via bf16x3 MFMA; agg = ushort-max of
// non-negative bf16 bits; agg stored bf16.
#define EPITCH 80    // m1 pitch (ushorts): 160 B rows
#define M2PITCH 132  // m2 pitch (ushorts): 264 B rows
__global__ __launch_bounds__(256) void edge_mfma(
    const float* __restrict__ ppf, const int* __restrict__ nbr,
    const float* __restrict__ cw1, const float* __restrict__ cb1,
    const ushort* __restrict__ C2h, const ushort* __restrict__ C2l,
    const float* __restrict__ cb2, ushort* __restrict__ aggB) {
  __shared__ float posL[128 * 3];
  __shared__ int nbrL[144];
  __shared__ __align__(16) ushort buf[2 * 144 * EPITCH];  // m1h|m1l, reused as m2
  ushort* m1h = buf;
  ushort* m1l = buf + 144 * EPITCH;
  ushort* m2L = buf;   // 144*132 = 19008 <= 23040

  const int b = blockIdx.x, t = threadIdx.x;
  const int p = b >> 3, off = (b & 7) * 16;
  for (int i = t; i < 384; i += 256) posL[i] = ppf[p * 384 + i];
  if (t < 144) nbrL[t] = nbr[(p * 128 + off) * 9 + t];
  __syncthreads();

  // phase 1: m1[e][c] = relu(feat . cw1[:,c] + cb1[c]) -> bf16 hi/lo
  {
    const int c = t & 63, eg = t >> 6;
    float w1c[6];
    #pragma unroll
    for (int q = 0; q < 6; ++q) w1c[q] = cw1[q * 64 + c];
    const float b1c = cb1[c];
    for (int e = eg; e < 144; e += 4) {
      const int pl = e / 9;
      const int j = nbrL[e];
      const int jj = j < 0 ? 0 : j;
      const int ctr = off + pl;
      const float nx = posL[jj * 3], ny = posL[jj * 3 + 1], nz = posL[jj * 3 + 2];
      const float cx = posL[ctr * 3], cy = posL[ctr * 3 + 1], cz = posL[ctr * 3 + 2];
      float v = b1c + nx * w1c[0] + ny * w1c[1] + nz * w1c[2] +
                (nx - cx) * w1c[3] + (ny - cy) * w1c[4] + (nz - cz) * w1c[5];
      v = fmaxf(v, 0.f);
      const ushort hi = f2bf(v);
      m1h[e * EPITCH + c] = hi;
      m1l[e * EPITCH + c] = f2bf(v - bf2f(hi));
    }
  }
  __syncthreads();

  // phase 2: MFMA, wave w covers cols [w*32, w*32+32)
  const int w = t >> 6, l = t & 63, lrow = l & 15, quad = l >> 4;
  ffrag acc[9][2];
  {
    bfrag Bh[2][2], Bl[2][2];  // [nt][kt]
    #pragma unroll
    for (int nt = 0; nt < 2; ++nt)
      #pragma unroll
      for (int kt = 0; kt < 2; ++kt) {
        const int bi = (((w * 2 + nt) * 2 + kt) * 64 + l) * 8;
        Bh[nt][kt] = *(const bfrag*)&C2h[bi];
        Bl[nt][kt] = *(const bfrag*)&C2l[bi];
      }
    #pragma unroll
    for (int mt = 0; mt < 9; ++mt) {
      bfrag Ah[2], Al[2];
      #pragma unroll
      for (int kt = 0; kt < 2; ++kt) {
        const int ai = (mt * 16 + lrow) * EPITCH + kt * 32 + quad * 8;
        Ah[kt] = *(const bfrag*)&m1h[ai];
        Al[kt] = *(const bfrag*)&m1l[ai];
      }
      #pragma unroll
      for (int nt = 0; nt < 2; ++nt) {
        ffrag a = (ffrag){0.f, 0.f, 0.f, 0.f};
        #pragma unroll
        for (int kt = 0; kt < 2; ++kt) {
          a = MFMA16(Ah[kt], Bh[nt][kt], a);
          a = MFMA16(Ah[kt], Bl[nt][kt], a);
          a = MFMA16(Al[kt], Bh[nt][kt], a);
        }
        acc[mt][nt] = a;
      }
    }
  }
  __syncthreads();  // all m1 reads done; buf reusable

  // phase 3: epilogue bias+relu -> bf16 -> m2L
  {
    const float cbv0 = cb2[w * 32 + lrow];
    const float cbv1 = cb2[w * 32 + 16 + lrow];
    #pragma unroll
    for (int mt = 0; mt < 9; ++mt)
      #pragma unroll
      for (int nt = 0; nt < 2; ++nt) {
        const int col = w * 32 + nt * 16 + lrow;
        const float cbv = nt ? cbv1 : cbv0;
        #pragma unroll
        for (int r = 0; r < 4; ++r) {
          const int row = mt * 16 + quad * 4 + r;
          m2L[row * M2PITCH + col] = f2bf(fmaxf(acc[mt][nt][r] + cbv, 0.f));
        }
      }
  }
  __syncthreads();

  // phase 4: max over valid neighbors (ushort compare valid: all values >= 0)
  for (int o = t; o < 2048; o += 256) {
    const int pt = o >> 7, c = o & 127;
    ushort best = 0;
    #pragma unroll
    for (int s = 0; s < 9; ++s) {
      if (nbrL[pt * 9 + s] >= 0) {
        const ushort u = m2L[(pt * 9 + s) * M2PITCH + c];
        best = u > best ? u : best;
      }
    }
    aggB[(size_t)(p * 128 + off + pt) * 128 + c] = best;
  }
}

// ---------------------------------------------------------------- kernel E
// Final MLP via MFMA: 32 rows/block, 1024 blocks. agg now bf16.
#define PA  136   // aT pitch (bf16 elems)
#define PG1 520
#define PG2 264
__global__ __launch_bounds__(256) void final_mlp_mfma(
    const ushort* __restrict__ aggB, const float* __restrict__ B1,
    const ushort* __restrict__ W1p, const ushort* __restrict__ W2p,
    const ushort* __restrict__ W3p, const float* __restrict__ mb2,
    const float* __restrict__ mb3, float* __restrict__ rotw,
    float* __restrict__ out_rc) {
  __shared__ __align__(16) ushort g1T[32 * PG1];   // 33280 B
  __shared__ __align__(16) ushort reg2[32 * PG2];  // 16896 B: aT then g2T
  __shared__ float rotL[32 * 9];
  const int b = blockIdx.x, t = threadIdx.x;
  const int w = t >> 6, l = t & 63;
  const int lrow = l & 15, quad = l >> 4;
  int p, off;
  if (b < 512) { p = b >> 1;         off = (b & 1) * 32; }
  else         { p = (b - 512) >> 1; off = 64 + ((b - 512) & 1) * 32; }
  const int n0 = b * 32;

  // ---- stage 0: aggB tile (bf16) -> LDS aT[32][128] pitch PA
  {
    ushort* aT = reg2;
    const int r0 = t >> 3, sg = (t & 7) * 16;
    const ushort* src = aggB + (size_t)(p * 128 + off + r0) * 128 + sg;
    const uint4 v0 = *(const uint4*)src;
    const uint4 v1 = *(const uint4*)(src + 8);
    *(uint4*)&aT[r0 * PA + sg] = v0;
    *(uint4*)&aT[r0 * PA + sg + 8] = v1;
  }
  __syncthreads();

  // ---- stage 1: g1 (M=32, N=512, K=128); wave w: N cols [w*128, w*128+128)
  {
    const ushort* aT = reg2;
    bfrag a[2][4];
    #pragma unroll
    for (int mt = 0; mt < 2; ++mt)
      #pragma unroll
      for (int kt = 0; kt < 4; ++kt)
        a[mt][kt] = *(const bfrag*)&aT[(mt * 16 + lrow) * PA + kt * 32 + quad * 8];
    ffrag acc[2][8];
    #pragma unroll
    for (int nti = 0; nti < 8; ++nti) {
      const float bv = B1[p * 512 + (w * 8 + nti) * 16 + lrow];
      acc[0][nti] = (ffrag){bv, bv, bv, bv};
      acc[1][nti] = acc[0][nti];
    }
    #pragma unroll
    for (int nti = 0; nti < 8; ++nti) {
      const int nt = w * 8 + nti;
      #pragma unroll
      for (int kt = 0; kt < 4; ++kt) {
        const bfrag bb = *(const bfrag*)&W1p[((nt * 4 + kt) * 64 + l) * 8];
        acc[0][nti] = MFMA16(a[0][kt], bb, acc[0][nti]);
        acc[1][nti] = MFMA16(a[1][kt], bb, acc[1][nti]);
      }
    }
    #pragma unroll
    for (int mt = 0; mt < 2; ++mt)
      #pragma unroll
      for (int nti = 0; nti < 8; ++nti) {
        const int col = (w * 8 + nti) * 16 + lrow;
        #pragma unroll
        for (int r = 0; r < 4; ++r)
          g1T[(mt * 16 + quad * 4 + r) * PG1 + col] = f2bf(fmaxf(acc[mt][nti][r], 0.f));
      }
  }
  __syncthreads();

  // ---- stage 2: g2 (M=32, N=256, K=512); wave w: N cols [w*64, w*64+64)
  {
    bfrag a[2][16];
    #pragma unroll
    for (int mt = 0; mt < 2; ++mt)
      #pragma unroll
      for (int kt = 0; kt < 16; ++kt)
        a[mt][kt] = *(const bfrag*)&g1T[(mt * 16 + lrow) * PG1 + kt * 32 + quad * 8];
    ffrag acc[2][4];
    #pragma unroll
    for (int nti = 0; nti < 4; ++nti) {
      acc[0][nti] = (ffrag){0.f, 0.f, 0.f, 0.f};
      acc[1][nti] = acc[0][nti];
    }
    #pragma unroll
    for (int nti = 0; nti < 4; ++nti) {
      const int nt = w * 4 + nti;
      #pragma unroll
      for (int kt = 0; kt < 16; ++kt) {
        const bfrag bb = *(const bfrag*)&W2p[((nt * 16 + kt) * 64 + l) * 8];
        acc[0][nti] = MFMA16(a[0][kt], bb, acc[0][nti]);
        acc[1][nti] = MFMA16(a[1][kt], bb, acc[1][nti]);
      }
    }
    ushort* g2T = reg2;
    #pragma unroll
    for (int mt = 0; mt < 2; ++mt)
      #pragma unroll
      for (int nti = 0; nti < 4; ++nti) {
        const int col = (w * 4 + nti) * 16 + lrow;
        const float bv = mb2[col];
        #pragma unroll
        for (int r = 0; r < 4; ++r)
          g2T[(mt * 16 + quad * 4 + r) * PG2 + col] =
              f2bf(fmaxf(acc[mt][nti][r] + bv, 0.f));
      }
  }
  __syncthreads();

  // ---- stage 3: g3 (M=32, N=16 padded, K=256); waves 0,1 take mt=w
  if (w < 2) {
    const ushort* g2T = reg2;
    ffrag acc = (ffrag){0.f, 0.f, 0.f, 0.f};
    #pragma unroll
    for (int kt = 0; kt < 8; ++kt) {
      const bfrag aa = *(const bfrag*)&g2T[(w * 16 + lrow) * PG2 + kt * 32 + quad * 8];
      const bfrag bb = *(const bfrag*)&W3p[(kt * 64 + l) * 8];
      acc = MFMA16(aa, bb, acc);
    }
    if (lrow < 9) {
      const float bv = mb3[lrow];
      #pragma unroll
      for (int r = 0; r < 4; ++r) {
        const int m = w * 16 + quad * 4 + r;
        const float u = fmaxf(acc[r] + bv, 0.f);
        rotL[m * 9 + lrow] = u;
        rotw[(size_t)(n0 + m) * 9 + lrow] = u;
      }
    }
  }
  __syncthreads();

  // ---- stage 4: rot_constrain
  for (int idx = t; idx < 288; idx += 256) {
    const int r = idx / 9, e = idx % 9, ii = e / 3, jj = e % 3;
    const float* R = &rotL[r * 9];
    out_rc[(size_t)(n0 + r) * 9 + e] =
        R[ii] * R[jj] + R[3 + ii] * R[3 + jj] + R[6 + ii] * R[6 + jj];
  }
}

// ---------------------------------------------------------------- kernel F
__global__ __launch_bounds__(256) void plane_k(const float* __restrict__ rotw,
                                               const float* __restrict__ ppf,
                                               float* __restrict__ out_plane) {
  const int q = blockIdx.x * 256 + threadIdx.x;  // < 524288
  const int n = q >> 4, tt = q & 15;
  const float* R = &rotw[n * 9];
  const int tx = tt & 3, ty = tt >> 2;
  const double step = 0.4 / 3.0;
  const float X = (tx == 3) ? 0.2f : (float)((double)tx * step - 0.2);
  const float Y = (ty == 3) ? 0.2f : (float)((double)ty * step - 0.2);
  const int m = q & (M2N - 1);
  int p, s;
  if (m < NPTS) { p = m >> 6; s = m & 63; }
  else          { const int mm = m - NPTS; p = mm >> 6; s = 64 + (mm & 63); }
  const float* C = &ppf[(p * 128 + s) * 3];
  #pragma unroll
  for (int i2 = 0; i2 < 3; ++i2) {
    const float d = R[i2 * 3 + 0] * X + R[i2 * 3 + 1] * Y;  // npts z == 0
    out_plane[q * 3 + i2] = d + C[i2];
  }
}

// ---------------------------------------------------------------- launch
extern "C" void kernel_launch(void* const* d_in, const int* in_sizes, int n_in,
                              void* d_out, int out_size, void* d_ws, size_t ws_size,
                              hipStream_t stream) {
  const float* pos       = (const float*)d_in[1];
  const float* local_fea = (const float*)d_in[4];
  const float* sw1 = (const float*)d_in[5];
  const float* sb1 = (const float*)d_in[6];
  const float* sw2 = (const float*)d_in[7];
  const float* sb2 = (const float*)d_in[8];
  const float* sw3 = (const float*)d_in[9];
  const float* sb3 = (const float*)d_in[10];
  const float* cw1 = (const float*)d_in[11];
  const float* cb1 = (const float*)d_in[12];
  const float* cw2 = (const float*)d_in[13];
  const float* cb2 = (const float*)d_in[14];
  const float* mw1 = (const float*)d_in[15];
  const float* mb1 = (const float*)d_in[16];
  const float* mw2 = (const float*)d_in[17];
  const float* mb2 = (const float*)d_in[18];
  const float* mw3 = (const float*)d_in[19];
  const float* mb3 = (const float*)d_in[20];

  char* ws = (char*)d_ws;
  double* A1d  = (double*)(ws + 0);         // 524288
  double* ppd  = (double*)(ws + 524288);    // 786432
  float*  B1   = (float*)(ws + 1310720);    // 524288
  float*  ppf  = (float*)(ws + 1835008);    // 393216
  int*    nbr  = (int*)(ws + 2228224);      // 1179648
  ushort* aggB = (ushort*)(ws + 3407872);   // 32768*128*2 = 8388608
  float*  rotw = (float*)(ws + 11796480);   // 1179648
  ushort* W1p  = (ushort*)(ws + 12976128);  // 131072
  ushort* W2p  = (ushort*)(ws + 13107200);  // 262144
  ushort* W3p  = (ushort*)(ws + 13369344);  // 8192
  ushort* C2h  = (ushort*)(ws + 13377536);  // 16384
  ushort* C2l  = (ushort*)(ws + 13393920);  // 16384 (end 13410304)

  float* out_plane = (float*)d_out;
  float* out_rc = out_plane + 1572864;  // P*2048*3

  patch_pre<<<256, 256, 0, stream>>>(local_fea, sw1, sb1, mw1, mb1, A1d, B1);
  point_mlp2<<<256, 256, 0, stream>>>(pos, sw1, sw2, sb2, sw3, sb3, A1d, ppd, ppf);
  neighbors_k<<<256, 128, 0, stream>>>(ppd, nbr);
  prepack_w<<<816, 256, 0, stream>>>(mw1, mw2, mw3, cw2, W1p, W2p, W3p, C2h, C2l);
  edge_mfma<<<2048, 256, 0, stream>>>(ppf, nbr, cw1, cb1, C2h, C2l, cb2, aggB);
  final_mlp_mfma<<<1024, 256, 0, stream>>>(aggB, B1, W1p, W2p, W3p, mb2, mb3, rotw, out_rc);
  plane_k<<<2048, 256, 0, stream>>>(rotw, ppf, out_plane);
}

// Round 6
// 347.008 us; speedup vs baseline: 2.0226x; 1.1176x over previous
//
#include <hip/hip_runtime.h>

// PlanePriorNet: P=256 patches x PT=64 pts, D=768. float32 I/O.
// Round 6: point MLP = round-4's exact fp64 VALU arithmetic (bit-identical ppd,
// proven top-k agreement) restructured into 512 half-patch blocks with h2s
// overlaid on h1T (68 KB LDS -> 2 blocks/CU). f64 MFMA reverted: its K-reduction
// reassociates fp64 sums and perturbed the discrete top-k (round-5 fail).

#define P 256
#define PT 64
#define NPTS 16384          // P*PT
#define M2N 32768           // 2*N
#define D 768

typedef __attribute__((ext_vector_type(8))) short bfrag;   // 8 x bf16 (4 VGPR)
typedef __attribute__((ext_vector_type(4))) float ffrag;   // 4 x f32 acc

#define MFMA16(a, b, c) __builtin_amdgcn_mfma_f32_16x16x32_bf16((a), (b), (c), 0, 0, 0)

// round-to-nearest-even fp32 -> bf16
__device__ __forceinline__ ushort f2bf(float x) {
  unsigned u = __float_as_uint(x);
  u = (u + 0x7FFFu + ((u >> 16) & 1u)) >> 16;
  return (ushort)u;
}
__device__ __forceinline__ float bf2f(ushort u) {
  return __uint_as_float((unsigned)u << 16);
}

// ---------------------------------------------------------------- kernel A
// Split by column chunk: chunk 0 -> A1d (fp64, 256 cols); chunks 1,2 -> B1 (fp32).
__global__ __launch_bounds__(256) void patch_pre2(
    const float* __restrict__ lf, const float* __restrict__ sw1,
    const float* __restrict__ sb1, const float* __restrict__ mw1,
    const float* __restrict__ mb1, double* __restrict__ A1d, float* __restrict__ B1) {
  __shared__ float lfs[768];
  const int b = blockIdx.x, t = threadIdx.x;
  const int p = b / 3, chunk = b % 3;
  for (int i = t; i < 768; i += 256) lfs[i] = lf[p * 768 + i];
  __syncthreads();
  if (chunk == 0) {
    double a = (double)sb1[t];
    for (int d = 0; d < 768; ++d)
      a += (double)lfs[d] * (double)sw1[d * 256 + t];
    A1d[p * 256 + t] = a;
  } else {
    const int c = (chunk - 1) * 256 + t;
    float bb = 0.f;
    for (int d = 0; d < 768; ++d)
      bb += lfs[d] * mw1[d * 512 + c];
    B1[p * 512 + c] = mb1[c] + bb;
  }
}

// ---------------------------------------------------------------- kernel B
// Point MLP, fp64 VALU (round-4 arithmetic, bit-identical), half-patch blocks.
// h1T [256][33] in LDS; h2s [32][129] overlays h1T after a barrier.
__global__ __launch_bounds__(256) void point_mlp4(
    const float* __restrict__ pos, const float* __restrict__ sw1,
    const float* __restrict__ sw2, const float* __restrict__ sb2,
    const float* __restrict__ sw3, const float* __restrict__ sb3,
    const double* __restrict__ A1d, double* __restrict__ ppd, float* __restrict__ ppf) {
  __shared__ double smemD[8448];   // h1T [k][pt] pitch 33; overlaid by h2s [32][129]
  __shared__ double posd[96];
  double* h1T = smemD;
  double* h2s = smemD;

  const int b = blockIdx.x, t = threadIdx.x;
  const int p = b >> 1, hb = b & 1;    // pts [hb*32, hb*32+32)
  if (t < 96) posd[t] = (double)pos[p * 192 + hb * 96 + t];
  __syncthreads();

  // stage 1: h1T[k=t][pt] = relu(A1[k] + pos . sw1'[k])   (round-4 expression)
  {
    const double a1 = A1d[p * 256 + t];
    const double w0 = (double)sw1[768 * 256 + t];
    const double w1 = (double)sw1[769 * 256 + t];
    const double w2 = (double)sw1[770 * 256 + t];
    for (int r = 0; r < 32; ++r) {
      const double* pp = &posd[r * 3];
      const double v = a1 + pp[0] * w0 + pp[1] * w1 + pp[2] * w2;
      h1T[t * 33 + r] = v > 0.0 ? v : 0.0;
    }
  }
  __syncthreads();

  // stage 2: h2[pt][c] = relu(sb2 + sum_k h1[pt][k]*sw2[k][c])  (round-4 order)
  {
    const int c = t & 127, grp = t >> 7;
    double acc[16];
    #pragma unroll
    for (int r = 0; r < 16; ++r) acc[r] = 0.0;
    for (int k = 0; k < 256; ++k) {
      const double w = (double)sw2[k * 128 + c];
      const double* hrow = &h1T[k * 33 + grp * 16];  // wave-broadcast reads
      #pragma unroll
      for (int r = 0; r < 16; ++r) acc[r] += hrow[r] * w;
    }
    __syncthreads();  // all h1T reads done; overlay h2s
    const double sb2d = (double)sb2[c];
    const int pb = grp * 16;
    #pragma unroll
    for (int r = 0; r < 16; ++r) {
      const double u = acc[r] + sb2d;
      h2s[(pb + r) * 129 + c] = u > 0.0 ? u : 0.0;
    }
  }
  __syncthreads();

  // stage 3: h3 + tanh + writes (96 threads; round-4 sequential c-sum)
  if (t < 96) {
    const int r = t / 3, j = t % 3;
    double u = (double)sb3[j];
    #pragma unroll 4
    for (int c = 0; c < 128; ++c)
      u += h2s[r * 129 + c] * (double)sw3[c * 3 + j];
    u = u > 0.0 ? u : 0.0;
    const int s = hb * 32 + r;
    const double po = posd[r * 3 + j];
    const double np_ = tanh(u) + po;
    const size_t rn = (size_t)(p * 128 + 64 + s) * 3 + j;
    const size_t ro = (size_t)(p * 128 + s) * 3 + j;
    ppd[rn] = np_;  ppf[rn] = (float)np_;
    ppd[ro] = po;   ppf[ro] = (float)po;
  }
}

// ---------------------------------------------------------------- kernel C
// Per patch row i: 9 smallest d2 among 128 candidates with d2<=R2,
// evict lexicographic max (d2, idx) == jax top_k(-d2) set semantics.
__global__ __launch_bounds__(128) void neighbors_k(const double* __restrict__ ppd,
                                                   int* __restrict__ nbr) {
  __shared__ double X[128], Y[128], Z[128];
  const int p = blockIdx.x, i = threadIdx.x;
  X[i] = ppd[(p * 128 + i) * 3 + 0];
  Y[i] = ppd[(p * 128 + i) * 3 + 1];
  Z[i] = ppd[(p * 128 + i) * 3 + 2];
  __syncthreads();
  const double R2d = 0.3 * 0.3;
  const double xi = X[i], yi = Y[i], zi = Z[i];
  double bd[9];
  int bix[9];
  #pragma unroll
  for (int k = 0; k < 9; ++k) { bd[k] = 1e300; bix[k] = 1 << 29; }
  for (int j = 0; j < 128; ++j) {
    const double dx = X[j] - xi, dy = Y[j] - yi, dz = Z[j] - zi;
    const double d2 = dx * dx + dy * dy + dz * dz;
    double mx = bd[0]; int mi = bix[0], mk = 0;
    #pragma unroll
    for (int k = 1; k < 9; ++k) {
      const bool g = (bd[k] > mx) || (bd[k] == mx && bix[k] > mi);
      if (g) { mx = bd[k]; mi = bix[k]; mk = k; }
    }
    if (d2 <= R2d && d2 < mx) {
      #pragma unroll
      for (int k = 0; k < 9; ++k)
        if (k == mk) { bd[k] = d2; bix[k] = j; }
    }
  }
  #pragma unroll
  for (int k = 0; k < 9; ++k)
    nbr[(p * 128 + i) * 9 + k] = (bd[k] <= R2d) ? bix[k] : -1;
}

// ---------------------------------------------------------------- kernel W
// Pack mw1[768:896], mw2, mw3(pad N->16), cw2(hi/lo) into MFMA B-fragment order:
// dst[((nt*KT + kt)*64 + lane)*8 + j] = W[kt*32 + (lane>>4)*8 + j][nt*16 + (lane&15)]
__global__ __launch_bounds__(256) void prepack_w(
    const float* __restrict__ mw1, const float* __restrict__ mw2,
    const float* __restrict__ mw3, const float* __restrict__ cw2,
    ushort* __restrict__ W1p, ushort* __restrict__ W2p, ushort* __restrict__ W3p,
    ushort* __restrict__ C2h, ushort* __restrict__ C2l) {
  const int idx = blockIdx.x * 256 + threadIdx.x;
  if (idx < 65536) {                       // W1p: K=128 (kt<4), N=512 (nt<32)
    const int j = idx & 7, l = (idx >> 3) & 63, kt = (idx >> 9) & 3, nt = idx >> 11;
    const int k = kt * 32 + (l >> 4) * 8 + j, n = nt * 16 + (l & 15);
    W1p[idx] = f2bf(mw1[(768 + k) * 512 + n]);
  } else if (idx < 196608) {               // W2p: K=512 (kt<16), N=256 (nt<16)
    const int q = idx - 65536;
    const int j = q & 7, l = (q >> 3) & 63, kt = (q >> 9) & 15, nt = q >> 13;
    const int k = kt * 32 + (l >> 4) * 8 + j, n = nt * 16 + (l & 15);
    W2p[q] = f2bf(mw2[k * 256 + n]);
  } else if (idx < 200704) {               // W3p: K=256 (kt<8), N=9 padded to 16
    const int q = idx - 196608;
    const int j = q & 7, l = (q >> 3) & 63, kt = q >> 9;
    const int k = kt * 32 + (l >> 4) * 8 + j, n = l & 15;
    W3p[q] = (n < 9) ? f2bf(mw3[k * 9 + n]) : (ushort)0;
  } else if (idx < 208896) {               // C2h/C2l: K=64 (kt<2), N=128 (nt<8)
    const int q = idx - 200704;
    const int j = q & 7, l = (q >> 3) & 63, kt = (q >> 9) & 1, nt = q >> 10;
    const int k = kt * 32 + (l >> 4) * 8 + j, n = nt * 16 + (l & 15);
    const float v = cw2[k * 128 + n];
    const ushort hi = f2bf(v);
    C2h[q] = hi;
    C2l[q] = f2bf(v - bf2f(hi));
  }
}

// ---------------------------------------------------------------- kernel D
// Edge MLP via MFMA: 16 pts/block (144 edges, M-tiles=9), N=128, K=64.
// m1 (K=6) on VALU -> LDS bf16 hi/lo; m2 via bf16x3 MFMA; agg = ushort-max of
// non-negative bf16 bits; agg stored bf16.
#define EPITCH 80    // m1 pitch (ushorts): 160 B rows
#define M2PITCH 132  // m2 pitch (ushorts): 264 B rows
__global__ __launch_bounds__(256) void edge_mfma(
    const float* __restrict__ ppf, const int* __restrict__ nbr,
    const float* __restrict__ cw1, const float* __restrict__ cb1,
    const ushort* __restrict__ C2h, const ushort* __restrict__ C2l,
    const float* __restrict__ cb2, ushort* __restrict__ aggB) {
  __shared__ float posL[128 * 3];
  __shared__ int nbrL[144];
  __shared__ __align__(16) ushort buf[2 * 144 * EPITCH];  // m1h|m1l, reused as m2
  ushort* m1h = buf;
  ushort* m1l = buf + 144 * EPITCH;
  ushort* m2L = buf;   // 144*132 = 19008 <= 23040

  const int b = blockIdx.x, t = threadIdx.x;
  const int p = b >> 3, off = (b & 7) * 16;
  for (int i = t; i < 384; i += 256) posL[i] = ppf[p * 384 + i];
  if (t < 144) nbrL[t] = nbr[(p * 128 + off) * 9 + t];
  __syncthreads();

  // phase 1: m1[e][c] = relu(feat . cw1[:,c] + cb1[c]) -> bf16 hi/lo
  {
    const int c = t & 63, eg = t >> 6;
    float w1c[6];
    #pragma unroll
    for (int q = 0; q < 6; ++q) w1c[q] = cw1[q * 64 + c];
    const float b1c = cb1[c];
    for (int e = eg; e < 144; e += 4) {
      const int pl = e / 9;
      const int j = nbrL[e];
      const int jj = j < 0 ? 0 : j;
      const int ctr = off + pl;
      const float nx = posL[jj * 3], ny = posL[jj * 3 + 1], nz = posL[jj * 3 + 2];
      const float cx = posL[ctr * 3], cy = posL[ctr * 3 + 1], cz = posL[ctr * 3 + 2];
      float v = b1c + nx * w1c[0] + ny * w1c[1] + nz * w1c[2] +
                (nx - cx) * w1c[3] + (ny - cy) * w1c[4] + (nz - cz) * w1c[5];
      v = fmaxf(v, 0.f);
      const ushort hi = f2bf(v);
      m1h[e * EPITCH + c] = hi;
      m1l[e * EPITCH + c] = f2bf(v - bf2f(hi));
    }
  }
  __syncthreads();

  // phase 2: MFMA, wave w covers cols [w*32, w*32+32)
  const int w = t >> 6, l = t & 63, lrow = l & 15, quad = l >> 4;
  ffrag acc[9][2];
  {
    bfrag Bh[2][2], Bl[2][2];  // [nt][kt]
    #pragma unroll
    for (int nt = 0; nt < 2; ++nt)
      #pragma unroll
      for (int kt = 0; kt < 2; ++kt) {
        const int bi = (((w * 2 + nt) * 2 + kt) * 64 + l) * 8;
        Bh[nt][kt] = *(const bfrag*)&C2h[bi];
        Bl[nt][kt] = *(const bfrag*)&C2l[bi];
      }
    #pragma unroll
    for (int mt = 0; mt < 9; ++mt) {
      bfrag Ah[2], Al[2];
      #pragma unroll
      for (int kt = 0; kt < 2; ++kt) {
        const int ai = (mt * 16 + lrow) * EPITCH + kt * 32 + quad * 8;
        Ah[kt] = *(const bfrag*)&m1h[ai];
        Al[kt] = *(const bfrag*)&m1l[ai];
      }
      #pragma unroll
      for (int nt = 0; nt < 2; ++nt) {
        ffrag a = (ffrag){0.f, 0.f, 0.f, 0.f};
        #pragma unroll
        for (int kt = 0; kt < 2; ++kt) {
          a = MFMA16(Ah[kt], Bh[nt][kt], a);
          a = MFMA16(Ah[kt], Bl[nt][kt], a);
          a = MFMA16(Al[kt], Bh[nt][kt], a);
        }
        acc[mt][nt] = a;
      }
    }
  }
  __syncthreads();  // all m1 reads done; buf reusable

  // phase 3: epilogue bias+relu -> bf16 -> m2L
  {
    const float cbv0 = cb2[w * 32 + lrow];
    const float cbv1 = cb2[w * 32 + 16 + lrow];
    #pragma unroll
    for (int mt = 0; mt < 9; ++mt)
      #pragma unroll
      for (int nt = 0; nt < 2; ++nt) {
        const int col = w * 32 + nt * 16 + lrow;
        const float cbv = nt ? cbv1 : cbv0;
        #pragma unroll
        for (int r = 0; r < 4; ++r) {
          const int row = mt * 16 + quad * 4 + r;
          m2L[row * M2PITCH + col] = f2bf(fmaxf(acc[mt][nt][r] + cbv, 0.f));
        }
      }
  }
  __syncthreads();

  // phase 4: max over valid neighbors (ushort compare valid: all values >= 0)
  for (int o = t; o < 2048; o += 256) {
    const int pt = o >> 7, c = o & 127;
    ushort best = 0;
    #pragma unroll
    for (int s = 0; s < 9; ++s) {
      if (nbrL[pt * 9 + s] >= 0) {
        const ushort u = m2L[(pt * 9 + s) * M2PITCH + c];
        best = u > best ? u : best;
      }
    }
    aggB[(size_t)(p * 128 + off + pt) * 128 + c] = best;
  }
}

// ---------------------------------------------------------------- kernel E
// Final MLP via MFMA: 32 rows/block, 1024 blocks. agg bf16.
#define PA  136   // aT pitch (bf16 elems)
#define PG1 520
#define PG2 264
__global__ __launch_bounds__(256) void final_mlp_mfma(
    const ushort* __restrict__ aggB, const float* __restrict__ B1,
    const ushort* __restrict__ W1p, const ushort* __restrict__ W2p,
    const ushort* __restrict__ W3p, const float* __restrict__ mb2,
    const float* __restrict__ mb3, float* __restrict__ rotw,
    float* __restrict__ out_rc) {
  __shared__ __align__(16) ushort g1T[32 * PG1];   // 33280 B
  __shared__ __align__(16) ushort reg2[32 * PG2];  // 16896 B: aT then g2T
  __shared__ float rotL[32 * 9];
  const int b = blockIdx.x, t = threadIdx.x;
  const int w = t >> 6, l = t & 63;
  const int lrow = l & 15, quad = l >> 4;
  int p, off;
  if (b < 512) { p = b >> 1;         off = (b & 1) * 32; }
  else         { p = (b - 512) >> 1; off = 64 + ((b - 512) & 1) * 32; }
  const int n0 = b * 32;

  // ---- stage 0: aggB tile (bf16) -> LDS aT[32][128] pitch PA
  {
    ushort* aT = reg2;
    const int r0 = t >> 3, sg = (t & 7) * 16;
    const ushort* src = aggB + (size_t)(p * 128 + off + r0) * 128 + sg;
    const uint4 v0 = *(const uint4*)src;
    const uint4 v1 = *(const uint4*)(src + 8);
    *(uint4*)&aT[r0 * PA + sg] = v0;
    *(uint4*)&aT[r0 * PA + sg + 8] = v1;
  }
  __syncthreads();

  // ---- stage 1: g1 (M=32, N=512, K=128); wave w: N cols [w*128, w*128+128)
  {
    const ushort* aT = reg2;
    bfrag a[2][4];
    #pragma unroll
    for (int mt = 0; mt < 2; ++mt)
      #pragma unroll
      for (int kt = 0; kt < 4; ++kt)
        a[mt][kt] = *(const bfrag*)&aT[(mt * 16 + lrow) * PA + kt * 32 + quad * 8];
    ffrag acc[2][8];
    #pragma unroll
    for (int nti = 0; nti < 8; ++nti) {
      const float bv = B1[p * 512 + (w * 8 + nti) * 16 + lrow];
      acc[0][nti] = (ffrag){bv, bv, bv, bv};
      acc[1][nti] = acc[0][nti];
    }
    #pragma unroll
    for (int nti = 0; nti < 8; ++nti) {
      const int nt = w * 8 + nti;
      #pragma unroll
      for (int kt = 0; kt < 4; ++kt) {
        const bfrag bb = *(const bfrag*)&W1p[((nt * 4 + kt) * 64 + l) * 8];
        acc[0][nti] = MFMA16(a[0][kt], bb, acc[0][nti]);
        acc[1][nti] = MFMA16(a[1][kt], bb, acc[1][nti]);
      }
    }
    #pragma unroll
    for (int mt = 0; mt < 2; ++mt)
      #pragma unroll
      for (int nti = 0; nti < 8; ++nti) {
        const int col = (w * 8 + nti) * 16 + lrow;
        #pragma unroll
        for (int r = 0; r < 4; ++r)
          g1T[(mt * 16 + quad * 4 + r) * PG1 + col] = f2bf(fmaxf(acc[mt][nti][r], 0.f));
      }
  }
  __syncthreads();

  // ---- stage 2: g2 (M=32, N=256, K=512); wave w: N cols [w*64, w*64+64)
  {
    bfrag a[2][16];
    #pragma unroll
    for (int mt = 0; mt < 2; ++mt)
      #pragma unroll
      for (int kt = 0; kt < 16; ++kt)
        a[mt][kt] = *(const bfrag*)&g1T[(mt * 16 + lrow) * PG1 + kt * 32 + quad * 8];
    ffrag acc[2][4];
    #pragma unroll
    for (int nti = 0; nti < 4; ++nti) {
      acc[0][nti] = (ffrag){0.f, 0.f, 0.f, 0.f};
      acc[1][nti] = acc[0][nti];
    }
    #pragma unroll
    for (int nti = 0; nti < 4; ++nti) {
      const int nt = w * 4 + nti;
      #pragma unroll
      for (int kt = 0; kt < 16; ++kt) {
        const bfrag bb = *(const bfrag*)&W2p[((nt * 16 + kt) * 64 + l) * 8];
        acc[0][nti] = MFMA16(a[0][kt], bb, acc[0][nti]);
        acc[1][nti] = MFMA16(a[1][kt], bb, acc[1][nti]);
      }
    }
    ushort* g2T = reg2;
    #pragma unroll
    for (int mt = 0; mt < 2; ++mt)
      #pragma unroll
      for (int nti = 0; nti < 4; ++nti) {
        const int col = (w * 4 + nti) * 16 + lrow;
        const float bv = mb2[col];
        #pragma unroll
        for (int r = 0; r < 4; ++r)
          g2T[(mt * 16 + quad * 4 + r) * PG2 + col] =
              f2bf(fmaxf(acc[mt][nti][r] + bv, 0.f));
      }
  }
  __syncthreads();

  // ---- stage 3: g3 (M=32, N=16 padded, K=256); waves 0,1 take mt=w
  if (w < 2) {
    const ushort* g2T = reg2;
    ffrag acc = (ffrag){0.f, 0.f, 0.f, 0.f};
    #pragma unroll
    for (int kt = 0; kt < 8; ++kt) {
      const bfrag aa = *(const bfrag*)&g2T[(w * 16 + lrow) * PG2 + kt * 32 + quad * 8];
      const bfrag bb = *(const bfrag*)&W3p[(kt * 64 + l) * 8];
      acc = MFMA16(aa, bb, acc);
    }
    if (lrow < 9) {
      const float bv = mb3[lrow];
      #pragma unroll
      for (int r = 0; r < 4; ++r) {
        const int m = w * 16 + quad * 4 + r;
        const float u = fmaxf(acc[r] + bv, 0.f);
        rotL[m * 9 + lrow] = u;
        rotw[(size_t)(n0 + m) * 9 + lrow] = u;
      }
    }
  }
  __syncthreads();

  // ---- stage 4: rot_constrain
  for (int idx = t; idx < 288; idx += 256) {
    const int r = idx / 9, e = idx % 9, ii = e / 3, jj = e % 3;
    const float* R = &rotL[r * 9];
    out_rc[(size_t)(n0 + r) * 9 + e] =
        R[ii] * R[jj] + R[3 + ii] * R[3 + jj] + R[6 + ii] * R[6 + jj];
  }
}

// ---------------------------------------------------------------- kernel F
__global__ __launch_bounds__(256) void plane_k(const float* __restrict__ rotw,
                                               const float* __restrict__ ppf,
                                               float* __restrict__ out_plane) {
  const int q = blockIdx.x * 256 + threadIdx.x;  // < 524288
  const int n = q >> 4, tt = q & 15;
  const float* R = &rotw[n * 9];
  const int tx = tt & 3, ty = tt >> 2;
  const double step = 0.4 / 3.0;
  const float X = (tx == 3) ? 0.2f : (float)((double)tx * step - 0.2);
  const float Y = (ty == 3) ? 0.2f : (float)((double)ty * step - 0.2);
  const int m = q & (M2N - 1);
  int p, s;
  if (m < NPTS) { p = m >> 6; s = m & 63; }
  else          { const int mm = m - NPTS; p = mm >> 6; s = 64 + (mm & 63); }
  const float* C = &ppf[(p * 128 + s) * 3];
  #pragma unroll
  for (int i2 = 0; i2 < 3; ++i2) {
    const float d = R[i2 * 3 + 0] * X + R[i2 * 3 + 1] * Y;  // npts z == 0
    out_plane[q * 3 + i2] = d + C[i2];
  }
}

// ---------------------------------------------------------------- launch
extern "C" void kernel_launch(void* const* d_in, const int* in_sizes, int n_in,
                              void* d_out, int out_size, void* d_ws, size_t ws_size,
                              hipStream_t stream) {
  const float* pos       = (const float*)d_in[1];
  const float* local_fea = (const float*)d_in[4];
  const float* sw1 = (const float*)d_in[5];
  const float* sb1 = (const float*)d_in[6];
  const float* sw2 = (const float*)d_in[7];
  const float* sb2 = (const float*)d_in[8];
  const float* sw3 = (const float*)d_in[9];
  const float* sb3 = (const float*)d_in[10];
  const float* cw1 = (const float*)d_in[11];
  const float* cb1 = (const float*)d_in[12];
  const float* cw2 = (const float*)d_in[13];
  const float* cb2 = (const float*)d_in[14];
  const float* mw1 = (const float*)d_in[15];
  const float* mb1 = (const float*)d_in[16];
  const float* mw2 = (const float*)d_in[17];
  const float* mb2 = (const float*)d_in[18];
  const float* mw3 = (const float*)d_in[19];
  const float* mb3 = (const float*)d_in[20];

  char* ws = (char*)d_ws;
  double* A1d  = (double*)(ws + 0);         // 524288
  double* ppd  = (double*)(ws + 524288);    // 786432
  float*  B1   = (float*)(ws + 1310720);    // 524288
  float*  ppf  = (float*)(ws + 1835008);    // 393216
  int*    nbr  = (int*)(ws + 2228224);      // 1179648
  ushort* aggB = (ushort*)(ws + 3407872);   // 8388608
  float*  rotw = (float*)(ws + 11796480);   // 1179648
  ushort* W1p  = (ushort*)(ws + 12976128);  // 131072
  ushort* W2p  = (ushort*)(ws + 13107200);  // 262144
  ushort* W3p  = (ushort*)(ws + 13369344);  // 8192
  ushort* C2h  = (ushort*)(ws + 13377536);  // 16384
  ushort* C2l  = (ushort*)(ws + 13393920);  // 16384 (end 13410304)

  float* out_plane = (float*)d_out;
  float* out_rc = out_plane + 1572864;  // P*2048*3

  patch_pre2<<<768, 256, 0, stream>>>(local_fea, sw1, sb1, mw1, mb1, A1d, B1);
  point_mlp4<<<512, 256, 0, stream>>>(pos, sw1, sw2, sb2, sw3, sb3, A1d, ppd, ppf);
  neighbors_k<<<256, 128, 0, stream>>>(ppd, nbr);
  prepack_w<<<816, 256, 0, stream>>>(mw1, mw2, mw3, cw2, W1p, W2p, W3p, C2h, C2l);
  edge_mfma<<<2048, 256, 0, stream>>>(ppf, nbr, cw1, cb1, C2h, C2l, cb2, aggB);
  final_mlp_mfma<<<1024, 256, 0, stream>>>(aggB, B1, W1p, W2p, W3p, mb2, mb3, rotw, out_rc);
  plane_k<<<2048, 256, 0, stream>>>(rotw, ppf, out_plane);
}

// Round 7
// 341.924 us; speedup vs baseline: 2.0527x; 1.0149x over previous
//
#include <hip/hip_runtime.h>

// PlanePriorNet: P=256 patches x PT=64 pts, D=768. float32 I/O.
// Round 7: point MLP -> quarter-patch blocks (16 pts, 1024 blocks, ~52 KB LDS
// -> 4 blocks/CU). Arithmetic expressions verbatim from round-4 (bit-identical
// fp64 chain feeding the discrete top-k; round-5 proved reassociation fails).

#define P 256
#define PT 64
#define NPTS 16384          // P*PT
#define M2N 32768           // 2*N
#define D 768

typedef __attribute__((ext_vector_type(8))) short bfrag;   // 8 x bf16 (4 VGPR)
typedef __attribute__((ext_vector_type(4))) float ffrag;   // 4 x f32 acc

#define MFMA16(a, b, c) __builtin_amdgcn_mfma_f32_16x16x32_bf16((a), (b), (c), 0, 0, 0)

// round-to-nearest-even fp32 -> bf16
__device__ __forceinline__ ushort f2bf(float x) {
  unsigned u = __float_as_uint(x);
  u = (u + 0x7FFFu + ((u >> 16) & 1u)) >> 16;
  return (ushort)u;
}
__device__ __forceinline__ float bf2f(ushort u) {
  return __uint_as_float((unsigned)u << 16);
}

// ---------------------------------------------------------------- kernel A
// Split by column chunk: chunk 0 -> A1d (fp64, 256 cols); chunks 1,2 -> B1 (fp32).
__global__ __launch_bounds__(256) void patch_pre2(
    const float* __restrict__ lf, const float* __restrict__ sw1,
    const float* __restrict__ sb1, const float* __restrict__ mw1,
    const float* __restrict__ mb1, double* __restrict__ A1d, float* __restrict__ B1) {
  __shared__ float lfs[768];
  const int b = blockIdx.x, t = threadIdx.x;
  const int p = b / 3, chunk = b % 3;
  for (int i = t; i < 768; i += 256) lfs[i] = lf[p * 768 + i];
  __syncthreads();
  if (chunk == 0) {
    double a = (double)sb1[t];
    for (int d = 0; d < 768; ++d)
      a += (double)lfs[d] * (double)sw1[d * 256 + t];
    A1d[p * 256 + t] = a;
  } else {
    const int c = (chunk - 1) * 256 + t;
    float bb = 0.f;
    for (int d = 0; d < 768; ++d)
      bb += lfs[d] * mw1[d * 512 + c];
    B1[p * 512 + c] = mb1[c] + bb;
  }
}

// ---------------------------------------------------------------- kernel B
// Point MLP, fp64 VALU (round-4 arithmetic, bit-identical), quarter-patch blocks.
// h1T [256][17] doubles; h2s [16][129] doubles overlays h1T after a barrier.
__global__ __launch_bounds__(256) void point_mlp5(
    const float* __restrict__ pos, const float* __restrict__ sw1,
    const float* __restrict__ sw2, const float* __restrict__ sb2,
    const float* __restrict__ sw3, const float* __restrict__ sb3,
    const double* __restrict__ A1d, double* __restrict__ ppd, float* __restrict__ ppf) {
  __shared__ double smemD[4352];   // h1T [k][pt] pitch 17 (34816 B); h2s overlay
  __shared__ double posd[48];
  double* h1T = smemD;
  double* h2s = smemD;

  const int b = blockIdx.x, t = threadIdx.x;
  const int p = b >> 2, qb = b & 3;    // pts [qb*16, qb*16+16)
  if (t < 48) posd[t] = (double)pos[p * 192 + qb * 48 + t];
  __syncthreads();

  // stage 1: h1T[k=t][pt] = relu(A1[k] + pos . sw1'[k])   (round-4 expression)
  {
    const double a1 = A1d[p * 256 + t];
    const double w0 = (double)sw1[768 * 256 + t];
    const double w1 = (double)sw1[769 * 256 + t];
    const double w2 = (double)sw1[770 * 256 + t];
    for (int r = 0; r < 16; ++r) {
      const double* pp = &posd[r * 3];
      const double v = a1 + pp[0] * w0 + pp[1] * w1 + pp[2] * w2;
      h1T[t * 17 + r] = v > 0.0 ? v : 0.0;
    }
  }
  __syncthreads();

  // stage 2: h2[pt][c] = relu(sb2 + sum_k h1[pt][k]*sw2[k][c])  (round-4 order)
  {
    const int c = t & 127, grp = t >> 7;
    double acc[8];
    #pragma unroll
    for (int r = 0; r < 8; ++r) acc[r] = 0.0;
    for (int k = 0; k < 256; ++k) {
      const double w = (double)sw2[k * 128 + c];
      const double* hrow = &h1T[k * 17 + grp * 8];  // wave-broadcast reads
      #pragma unroll
      for (int r = 0; r < 8; ++r) acc[r] += hrow[r] * w;
    }
    __syncthreads();  // all h1T reads done; overlay h2s
    const double sb2d = (double)sb2[c];
    const int pb = grp * 8;
    #pragma unroll
    for (int r = 0; r < 8; ++r) {
      const double u = acc[r] + sb2d;
      h2s[(pb + r) * 129 + c] = u > 0.0 ? u : 0.0;
    }
  }
  __syncthreads();

  // stage 3: h3 + tanh + writes (48 threads; round-4 sequential c-sum)
  if (t < 48) {
    const int r = t / 3, j = t % 3;
    double u = (double)sb3[j];
    #pragma unroll 4
    for (int c = 0; c < 128; ++c)
      u += h2s[r * 129 + c] * (double)sw3[c * 3 + j];
    u = u > 0.0 ? u : 0.0;
    const int s = qb * 16 + r;
    const double po = posd[r * 3 + j];
    const double np_ = tanh(u) + po;
    const size_t rn = (size_t)(p * 128 + 64 + s) * 3 + j;
    const size_t ro = (size_t)(p * 128 + s) * 3 + j;
    ppd[rn] = np_;  ppf[rn] = (float)np_;
    ppd[ro] = po;   ppf[ro] = (float)po;
  }
}

// ---------------------------------------------------------------- kernel C
// Per patch row i: 9 smallest d2 among 128 candidates with d2<=R2,
// evict lexicographic max (d2, idx) == jax top_k(-d2) set semantics.
__global__ __launch_bounds__(128) void neighbors_k(const double* __restrict__ ppd,
                                                   int* __restrict__ nbr) {
  __shared__ double X[128], Y[128], Z[128];
  const int p = blockIdx.x, i = threadIdx.x;
  X[i] = ppd[(p * 128 + i) * 3 + 0];
  Y[i] = ppd[(p * 128 + i) * 3 + 1];
  Z[i] = ppd[(p * 128 + i) * 3 + 2];
  __syncthreads();
  const double R2d = 0.3 * 0.3;
  const double xi = X[i], yi = Y[i], zi = Z[i];
  double bd[9];
  int bix[9];
  #pragma unroll
  for (int k = 0; k < 9; ++k) { bd[k] = 1e300; bix[k] = 1 << 29; }
  for (int j = 0; j < 128; ++j) {
    const double dx = X[j] - xi, dy = Y[j] - yi, dz = Z[j] - zi;
    const double d2 = dx * dx + dy * dy + dz * dz;
    double mx = bd[0]; int mi = bix[0], mk = 0;
    #pragma unroll
    for (int k = 1; k < 9; ++k) {
      const bool g = (bd[k] > mx) || (bd[k] == mx && bix[k] > mi);
      if (g) { mx = bd[k]; mi = bix[k]; mk = k; }
    }
    if (d2 <= R2d && d2 < mx) {
      #pragma unroll
      for (int k = 0; k < 9; ++k)
        if (k == mk) { bd[k] = d2; bix[k] = j; }
    }
  }
  #pragma unroll
  for (int k = 0; k < 9; ++k)
    nbr[(p * 128 + i) * 9 + k] = (bd[k] <= R2d) ? bix[k] : -1;
}

// ---------------------------------------------------------------- kernel W
// Pack mw1[768:896], mw2, mw3(pad N->16), cw2(hi/lo) into MFMA B-fragment order:
// dst[((nt*KT + kt)*64 + lane)*8 + j] = W[kt*32 + (lane>>4)*8 + j][nt*16 + (lane&15)]
__global__ __launch_bounds__(256) void prepack_w(
    const float* __restrict__ mw1, const float* __restrict__ mw2,
    const float* __restrict__ mw3, const float* __restrict__ cw2,
    ushort* __restrict__ W1p, ushort* __restrict__ W2p, ushort* __restrict__ W3p,
    ushort* __restrict__ C2h, ushort* __restrict__ C2l) {
  const int idx = blockIdx.x * 256 + threadIdx.x;
  if (idx < 65536) {                       // W1p: K=128 (kt<4), N=512 (nt<32)
    const int j = idx & 7, l = (idx >> 3) & 63, kt = (idx >> 9) & 3, nt = idx >> 11;
    const int k = kt * 32 + (l >> 4) * 8 + j, n = nt * 16 + (l & 15);
    W1p[idx] = f2bf(mw1[(768 + k) * 512 + n]);
  } else if (idx < 196608) {               // W2p: K=512 (kt<16), N=256 (nt<16)
    const int q = idx - 65536;
    const int j = q & 7, l = (q >> 3) & 63, kt = (q >> 9) & 15, nt = q >> 13;
    const int k = kt * 32 + (l >> 4) * 8 + j, n = nt * 16 + (l & 15);
    W2p[q] = f2bf(mw2[k * 256 + n]);
  } else if (idx < 200704) {               // W3p: K=256 (kt<8), N=9 padded to 16
    const int q = idx - 196608;
    const int j = q & 7, l = (q >> 3) & 63, kt = q >> 9;
    const int k = kt * 32 + (l >> 4) * 8 + j, n = l & 15;
    W3p[q] = (n < 9) ? f2bf(mw3[k * 9 + n]) : (ushort)0;
  } else if (idx < 208896) {               // C2h/C2l: K=64 (kt<2), N=128 (nt<8)
    const int q = idx - 200704;
    const int j = q & 7, l = (q >> 3) & 63, kt = (q >> 9) & 1, nt = q >> 10;
    const int k = kt * 32 + (l >> 4) * 8 + j, n = nt * 16 + (l & 15);
    const float v = cw2[k * 128 + n];
    const ushort hi = f2bf(v);
    C2h[q] = hi;
    C2l[q] = f2bf(v - bf2f(hi));
  }
}

// ---------------------------------------------------------------- kernel D
// Edge MLP via MFMA: 16 pts/block (144 edges, M-tiles=9), N=128, K=64.
// m1 (K=6) on VALU -> LDS bf16 hi/lo; m2 via bf16x3 MFMA; agg = ushort-max of
// non-negative bf16 bits; agg stored bf16.
#define EPITCH 80    // m1 pitch (ushorts): 160 B rows
#define M2PITCH 132  // m2 pitch (ushorts): 264 B rows
__global__ __launch_bounds__(256) void edge_mfma(
    const float* __restrict__ ppf, const int* __restrict__ nbr,
    const float* __restrict__ cw1, const float* __restrict__ cb1,
    const ushort* __restrict__ C2h, const ushort* __restrict__ C2l,
    const float* __restrict__ cb2, ushort* __restrict__ aggB) {
  __shared__ float posL[128 * 3];
  __shared__ int nbrL[144];
  __shared__ __align__(16) ushort buf[2 * 144 * EPITCH];  // m1h|m1l, reused as m2
  ushort* m1h = buf;
  ushort* m1l = buf + 144 * EPITCH;
  ushort* m2L = buf;   // 144*132 = 19008 <= 23040

  const int b = blockIdx.x, t = threadIdx.x;
  const int p = b >> 3, off = (b & 7) * 16;
  for (int i = t; i < 384; i += 256) posL[i] = ppf[p * 384 + i];
  if (t < 144) nbrL[t] = nbr[(p * 128 + off) * 9 + t];
  __syncthreads();

  // phase 1: m1[e][c] = relu(feat . cw1[:,c] + cb1[c]) -> bf16 hi/lo
  {
    const int c = t & 63, eg = t >> 6;
    float w1c[6];
    #pragma unroll
    for (int q = 0; q < 6; ++q) w1c[q] = cw1[q * 64 + c];
    const float b1c = cb1[c];
    for (int e = eg; e < 144; e += 4) {
      const int pl = e / 9;
      const int j = nbrL[e];
      const int jj = j < 0 ? 0 : j;
      const int ctr = off + pl;
      const float nx = posL[jj * 3], ny = posL[jj * 3 + 1], nz = posL[jj * 3 + 2];
      const float cx = posL[ctr * 3], cy = posL[ctr * 3 + 1], cz = posL[ctr * 3 + 2];
      float v = b1c + nx * w1c[0] + ny * w1c[1] + nz * w1c[2] +
                (nx - cx) * w1c[3] + (ny - cy) * w1c[4] + (nz - cz) * w1c[5];
      v = fmaxf(v, 0.f);
      const ushort hi = f2bf(v);
      m1h[e * EPITCH + c] = hi;
      m1l[e * EPITCH + c] = f2bf(v - bf2f(hi));
    }
  }
  __syncthreads();

  // phase 2: MFMA, wave w covers cols [w*32, w*32+32)
  const int w = t >> 6, l = t & 63, lrow = l & 15, quad = l >> 4;
  ffrag acc[9][2];
  {
    bfrag Bh[2][2], Bl[2][2];  // [nt][kt]
    #pragma unroll
    for (int nt = 0; nt < 2; ++nt)
      #pragma unroll
      for (int kt = 0; kt < 2; ++kt) {
        const int bi = (((w * 2 + nt) * 2 + kt) * 64 + l) * 8;
        Bh[nt][kt] = *(const bfrag*)&C2h[bi];
        Bl[nt][kt] = *(const bfrag*)&C2l[bi];
      }
    #pragma unroll
    for (int mt = 0; mt < 9; ++mt) {
      bfrag Ah[2], Al[2];
      #pragma unroll
      for (int kt = 0; kt < 2; ++kt) {
        const int ai = (mt * 16 + lrow) * EPITCH + kt * 32 + quad * 8;
        Ah[kt] = *(const bfrag*)&m1h[ai];
        Al[kt] = *(const bfrag*)&m1l[ai];
      }
      #pragma unroll
      for (int nt = 0; nt < 2; ++nt) {
        ffrag a = (ffrag){0.f, 0.f, 0.f, 0.f};
        #pragma unroll
        for (int kt = 0; kt < 2; ++kt) {
          a = MFMA16(Ah[kt], Bh[nt][kt], a);
          a = MFMA16(Ah[kt], Bl[nt][kt], a);
          a = MFMA16(Al[kt], Bh[nt][kt], a);
        }
        acc[mt][nt] = a;
      }
    }
  }
  __syncthreads();  // all m1 reads done; buf reusable

  // phase 3: epilogue bias+relu -> bf16 -> m2L
  {
    const float cbv0 = cb2[w * 32 + lrow];
    const float cbv1 = cb2[w * 32 + 16 + lrow];
    #pragma unroll
    for (int mt = 0; mt < 9; ++mt)
      #pragma unroll
      for (int nt = 0; nt < 2; ++nt) {
        const int col = w * 32 + nt * 16 + lrow;
        const float cbv = nt ? cbv1 : cbv0;
        #pragma unroll
        for (int r = 0; r < 4; ++r) {
          const int row = mt * 16 + quad * 4 + r;
          m2L[row * M2PITCH + col] = f2bf(fmaxf(acc[mt][nt][r] + cbv, 0.f));
        }
      }
  }
  __syncthreads();

  // phase 4: max over valid neighbors (ushort compare valid: all values >= 0)
  for (int o = t; o < 2048; o += 256) {
    const int pt = o >> 7, c = o & 127;
    ushort best = 0;
    #pragma unroll
    for (int s = 0; s < 9; ++s) {
      if (nbrL[pt * 9 + s] >= 0) {
        const ushort u = m2L[(pt * 9 + s) * M2PITCH + c];
        best = u > best ? u : best;
      }
    }
    aggB[(size_t)(p * 128 + off + pt) * 128 + c] = best;
  }
}

// ---------------------------------------------------------------- kernel E
// Final MLP via MFMA: 32 rows/block, 1024 blocks. agg bf16.
#define PA  136   // aT pitch (bf16 elems)
#define PG1 520
#define PG2 264
__global__ __launch_bounds__(256) void final_mlp_mfma(
    const ushort* __restrict__ aggB, const float* __restrict__ B1,
    const ushort* __restrict__ W1p, const ushort* __restrict__ W2p,
    const ushort* __restrict__ W3p, const float* __restrict__ mb2,
    const float* __restrict__ mb3, float* __restrict__ rotw,
    float* __restrict__ out_rc) {
  __shared__ __align__(16) ushort g1T[32 * PG1];   // 33280 B
  __shared__ __align__(16) ushort reg2[32 * PG2];  // 16896 B: aT then g2T
  __shared__ float rotL[32 * 9];
  const int b = blockIdx.x, t = threadIdx.x;
  const int w = t >> 6, l = t & 63;
  const int lrow = l & 15, quad = l >> 4;
  int p, off;
  if (b < 512) { p = b >> 1;         off = (b & 1) * 32; }
  else         { p = (b - 512) >> 1; off = 64 + ((b - 512) & 1) * 32; }
  const int n0 = b * 32;

  // ---- stage 0: aggB tile (bf16) -> LDS aT[32][128] pitch PA
  {
    ushort* aT = reg2;
    const int r0 = t >> 3, sg = (t & 7) * 16;
    const ushort* src = aggB + (size_t)(p * 128 + off + r0) * 128 + sg;
    const uint4 v0 = *(const uint4*)src;
    const uint4 v1 = *(const uint4*)(src + 8);
    *(uint4*)&aT[r0 * PA + sg] = v0;
    *(uint4*)&aT[r0 * PA + sg + 8] = v1;
  }
  __syncthreads();

  // ---- stage 1: g1 (M=32, N=512, K=128); wave w: N cols [w*128, w*128+128)
  {
    const ushort* aT = reg2;
    bfrag a[2][4];
    #pragma unroll
    for (int mt = 0; mt < 2; ++mt)
      #pragma unroll
      for (int kt = 0; kt < 4; ++kt)
        a[mt][kt] = *(const bfrag*)&aT[(mt * 16 + lrow) * PA + kt * 32 + quad * 8];
    ffrag acc[2][8];
    #pragma unroll
    for (int nti = 0; nti < 8; ++nti) {
      const float bv = B1[p * 512 + (w * 8 + nti) * 16 + lrow];
      acc[0][nti] = (ffrag){bv, bv, bv, bv};
      acc[1][nti] = acc[0][nti];
    }
    #pragma unroll
    for (int nti = 0; nti < 8; ++nti) {
      const int nt = w * 8 + nti;
      #pragma unroll
      for (int kt = 0; kt < 4; ++kt) {
        const bfrag bb = *(const bfrag*)&W1p[((nt * 4 + kt) * 64 + l) * 8];
        acc[0][nti] = MFMA16(a[0][kt], bb, acc[0][nti]);
        acc[1][nti] = MFMA16(a[1][kt], bb, acc[1][nti]);
      }
    }
    #pragma unroll
    for (int mt = 0; mt < 2; ++mt)
      #pragma unroll
      for (int nti = 0; nti < 8; ++nti) {
        const int col = (w * 8 + nti) * 16 + lrow;
        #pragma unroll
        for (int r = 0; r < 4; ++r)
          g1T[(mt * 16 + quad * 4 + r) * PG1 + col] = f2bf(fmaxf(acc[mt][nti][r], 0.f));
      }
  }
  __syncthreads();

  // ---- stage 2: g2 (M=32, N=256, K=512); wave w: N cols [w*64, w*64+64)
  {
    bfrag a[2][16];
    #pragma unroll
    for (int mt = 0; mt < 2; ++mt)
      #pragma unroll
      for (int kt = 0; kt < 16; ++kt)
        a[mt][kt] = *(const bfrag*)&g1T[(mt * 16 + lrow) * PG1 + kt * 32 + quad * 8];
    ffrag acc[2][4];
    #pragma unroll
    for (int nti = 0; nti < 4; ++nti) {
      acc[0][nti] = (ffrag){0.f, 0.f, 0.f, 0.f};
      acc[1][nti] = acc[0][nti];
    }
    #pragma unroll
    for (int nti = 0; nti < 4; ++nti) {
      const int nt = w * 4 + nti;
      #pragma unroll
      for (int kt = 0; kt < 16; ++kt) {
        const bfrag bb = *(const bfrag*)&W2p[((nt * 16 + kt) * 64 + l) * 8];
        acc[0][nti] = MFMA16(a[0][kt], bb, acc[0][nti]);
        acc[1][nti] = MFMA16(a[1][kt], bb, acc[1][nti]);
      }
    }
    ushort* g2T = reg2;
    #pragma unroll
    for (int mt = 0; mt < 2; ++mt)
      #pragma unroll
      for (int nti = 0; nti < 4; ++nti) {
        const int col = (w * 4 + nti) * 16 + lrow;
        const float bv = mb2[col];
        #pragma unroll
        for (int r = 0; r < 4; ++r)
          g2T[(mt * 16 + quad * 4 + r) * PG2 + col] =
              f2bf(fmaxf(acc[mt][nti][r] + bv, 0.f));
      }
  }
  __syncthreads();

  // ---- stage 3: g3 (M=32, N=16 padded, K=256); waves 0,1 take mt=w
  if (w < 2) {
    const ushort* g2T = reg2;
    ffrag acc = (ffrag){0.f, 0.f, 0.f, 0.f};
    #pragma unroll
    for (int kt = 0; kt < 8; ++kt) {
      const bfrag aa = *(const bfrag*)&g2T[(w * 16 + lrow) * PG2 + kt * 32 + quad * 8];
      const bfrag bb = *(const bfrag*)&W3p[(kt * 64 + l) * 8];
      acc = MFMA16(aa, bb, acc);
    }
    if (lrow < 9) {
      const float bv = mb3[lrow];
      #pragma unroll
      for (int r = 0; r < 4; ++r) {
        const int m = w * 16 + quad * 4 + r;
        const float u = fmaxf(acc[r] + bv, 0.f);
        rotL[m * 9 + lrow] = u;
        rotw[(size_t)(n0 + m) * 9 + lrow] = u;
      }
    }
  }
  __syncthreads();

  // ---- stage 4: rot_constrain
  for (int idx = t; idx < 288; idx += 256) {
    const int r = idx / 9, e = idx % 9, ii = e / 3, jj = e % 3;
    const float* R = &rotL[r * 9];
    out_rc[(size_t)(n0 + r) * 9 + e] =
        R[ii] * R[jj] + R[3 + ii] * R[3 + jj] + R[6 + ii] * R[6 + jj];
  }
}

// ---------------------------------------------------------------- kernel F
__global__ __launch_bounds__(256) void plane_k(const float* __restrict__ rotw,
                                               const float* __restrict__ ppf,
                                               float* __restrict__ out_plane) {
  const int q = blockIdx.x * 256 + threadIdx.x;  // < 524288
  const int n = q >> 4, tt = q & 15;
  const float* R = &rotw[n * 9];
  const int tx = tt & 3, ty = tt >> 2;
  const double step = 0.4 / 3.0;
  const float X = (tx == 3) ? 0.2f : (float)((double)tx * step - 0.2);
  const float Y = (ty == 3) ? 0.2f : (float)((double)ty * step - 0.2);
  const int m = q & (M2N - 1);
  int p, s;
  if (m < NPTS) { p = m >> 6; s = m & 63; }
  else          { const int mm = m - NPTS; p = mm >> 6; s = 64 + (mm & 63); }
  const float* C = &ppf[(p * 128 + s) * 3];
  #pragma unroll
  for (int i2 = 0; i2 < 3; ++i2) {
    const float d = R[i2 * 3 + 0] * X + R[i2 * 3 + 1] * Y;  // npts z == 0
    out_plane[q * 3 + i2] = d + C[i2];
  }
}

// ---------------------------------------------------------------- launch
extern "C" void kernel_launch(void* const* d_in, const int* in_sizes, int n_in,
                              void* d_out, int out_size, void* d_ws, size_t ws_size,
                              hipStream_t stream) {
  const float* pos       = (const float*)d_in[1];
  const float* local_fea = (const float*)d_in[4];
  const float* sw1 = (const float*)d_in[5];
  const float* sb1 = (const float*)d_in[6];
  const float* sw2 = (const float*)d_in[7];
  const float* sb2 = (const float*)d_in[8];
  const float* sw3 = (const float*)d_in[9];
  const float* sb3 = (const float*)d_in[10];
  const float* cw1 = (const float*)d_in[11];
  const float* cb1 = (const float*)d_in[12];
  const float* cw2 = (const float*)d_in[13];
  const float* cb2 = (const float*)d_in[14];
  const float* mw1 = (const float*)d_in[15];
  const float* mb1 = (const float*)d_in[16];
  const float* mw2 = (const float*)d_in[17];
  const float* mb2 = (const float*)d_in[18];
  const float* mw3 = (const float*)d_in[19];
  const float* mb3 = (const float*)d_in[20];

  char* ws = (char*)d_ws;
  double* A1d  = (double*)(ws + 0);         // 524288
  double* ppd  = (double*)(ws + 524288);    // 786432
  float*  B1   = (float*)(ws + 1310720);    // 524288
  float*  ppf  = (float*)(ws + 1835008);    // 393216
  int*    nbr  = (int*)(ws + 2228224);      // 1179648
  ushort* aggB = (ushort*)(ws + 3407872);   // 8388608
  float*  rotw = (float*)(ws + 11796480);   // 1179648
  ushort* W1p  = (ushort*)(ws + 12976128);  // 131072
  ushort* W2p  = (ushort*)(ws + 13107200);  // 262144
  ushort* W3p  = (ushort*)(ws + 13369344);  // 8192
  ushort* C2h  = (ushort*)(ws + 13377536);  // 16384
  ushort* C2l  = (ushort*)(ws + 13393920);  // 16384 (end 13410304)

  float* out_plane = (float*)d_out;
  float* out_rc = out_plane + 1572864;  // P*2048*3

  patch_pre2<<<768, 256, 0, stream>>>(local_fea, sw1, sb1, mw1, mb1, A1d, B1);
  point_mlp5<<<1024, 256, 0, stream>>>(pos, sw1, sw2, sb2, sw3, sb3, A1d, ppd, ppf);
  neighbors_k<<<256, 128, 0, stream>>>(ppd, nbr);
  prepack_w<<<816, 256, 0, stream>>>(mw1, mw2, mw3, cw2, W1p, W2p, W3p, C2h, C2l);
  edge_mfma<<<2048, 256, 0, stream>>>(ppf, nbr, cw1, cb1, C2h, C2l, cb2, aggB);
  final_mlp_mfma<<<1024, 256, 0, stream>>>(aggB, B1, W1p, W2p, W3p, mb2, mb3, rotw, out_rc);
  plane_k<<<2048, 256, 0, stream>>>(rotw, ppf, out_plane);
}

// Round 8
// 284.418 us; speedup vs baseline: 2.4677x; 1.2022x over previous
//
#include <hip/hip_runtime.h>

// PlanePriorNet: P=256 patches x PT=64 pts, D=768. float32 I/O.
// Round 8: neighbors_k -> branch-free u64-key sorted-insertion top-9 with
// 4-way candidate split + tree merge (512 thr/block). Key = (bits(d2)&~127)|idx
// makes lexicographic (d2,idx) a single u64 compare; d2 expression verbatim
// (bit-identical fp64 chain feeding the discrete top-k).

#define P 256
#define PT 64
#define NPTS 16384          // P*PT
#define M2N 32768           // 2*N
#define D 768
#define SENTK 0xFFFFFFFFFFFFFFFFull

typedef __attribute__((ext_vector_type(8))) short bfrag;   // 8 x bf16 (4 VGPR)
typedef __attribute__((ext_vector_type(4))) float ffrag;   // 4 x f32 acc

#define MFMA16(a, b, c) __builtin_amdgcn_mfma_f32_16x16x32_bf16((a), (b), (c), 0, 0, 0)

// round-to-nearest-even fp32 -> bf16
__device__ __forceinline__ ushort f2bf(float x) {
  unsigned u = __float_as_uint(x);
  u = (u + 0x7FFFu + ((u >> 16) & 1u)) >> 16;
  return (ushort)u;
}
__device__ __forceinline__ float bf2f(ushort u) {
  return __uint_as_float((unsigned)u << 16);
}

// ---------------------------------------------------------------- kernel A
// Split by column chunk: chunk 0 -> A1d (fp64, 256 cols); chunks 1,2 -> B1 (fp32).
__global__ __launch_bounds__(256) void patch_pre2(
    const float* __restrict__ lf, const float* __restrict__ sw1,
    const float* __restrict__ sb1, const float* __restrict__ mw1,
    const float* __restrict__ mb1, double* __restrict__ A1d, float* __restrict__ B1) {
  __shared__ float lfs[768];
  const int b = blockIdx.x, t = threadIdx.x;
  const int p = b / 3, chunk = b % 3;
  for (int i = t; i < 768; i += 256) lfs[i] = lf[p * 768 + i];
  __syncthreads();
  if (chunk == 0) {
    double a = (double)sb1[t];
    for (int d = 0; d < 768; ++d)
      a += (double)lfs[d] * (double)sw1[d * 256 + t];
    A1d[p * 256 + t] = a;
  } else {
    const int c = (chunk - 1) * 256 + t;
    float bb = 0.f;
    for (int d = 0; d < 768; ++d)
      bb += lfs[d] * mw1[d * 512 + c];
    B1[p * 512 + c] = mb1[c] + bb;
  }
}

// ---------------------------------------------------------------- kernel B
// Point MLP, fp64 VALU (round-4 arithmetic, bit-identical), quarter-patch blocks.
__global__ __launch_bounds__(256) void point_mlp5(
    const float* __restrict__ pos, const float* __restrict__ sw1,
    const float* __restrict__ sw2, const float* __restrict__ sb2,
    const float* __restrict__ sw3, const float* __restrict__ sb3,
    const double* __restrict__ A1d, double* __restrict__ ppd, float* __restrict__ ppf) {
  __shared__ double smemD[4352];   // h1T [k][pt] pitch 17 (34816 B); h2s overlay
  __shared__ double posd[48];
  double* h1T = smemD;
  double* h2s = smemD;

  const int b = blockIdx.x, t = threadIdx.x;
  const int p = b >> 2, qb = b & 3;    // pts [qb*16, qb*16+16)
  if (t < 48) posd[t] = (double)pos[p * 192 + qb * 48 + t];
  __syncthreads();

  // stage 1: h1T[k=t][pt] = relu(A1[k] + pos . sw1'[k])   (round-4 expression)
  {
    const double a1 = A1d[p * 256 + t];
    const double w0 = (double)sw1[768 * 256 + t];
    const double w1 = (double)sw1[769 * 256 + t];
    const double w2 = (double)sw1[770 * 256 + t];
    for (int r = 0; r < 16; ++r) {
      const double* pp = &posd[r * 3];
      const double v = a1 + pp[0] * w0 + pp[1] * w1 + pp[2] * w2;
      h1T[t * 17 + r] = v > 0.0 ? v : 0.0;
    }
  }
  __syncthreads();

  // stage 2: h2[pt][c] = relu(sb2 + sum_k h1[pt][k]*sw2[k][c])  (round-4 order)
  {
    const int c = t & 127, grp = t >> 7;
    double acc[8];
    #pragma unroll
    for (int r = 0; r < 8; ++r) acc[r] = 0.0;
    for (int k = 0; k < 256; ++k) {
      const double w = (double)sw2[k * 128 + c];
      const double* hrow = &h1T[k * 17 + grp * 8];  // wave-broadcast reads
      #pragma unroll
      for (int r = 0; r < 8; ++r) acc[r] += hrow[r] * w;
    }
    __syncthreads();  // all h1T reads done; overlay h2s
    const double sb2d = (double)sb2[c];
    const int pb = grp * 8;
    #pragma unroll
    for (int r = 0; r < 8; ++r) {
      const double u = acc[r] + sb2d;
      h2s[(pb + r) * 129 + c] = u > 0.0 ? u : 0.0;
    }
  }
  __syncthreads();

  // stage 3: h3 + tanh + writes (48 threads; round-4 sequential c-sum)
  if (t < 48) {
    const int r = t / 3, j = t % 3;
    double u = (double)sb3[j];
    #pragma unroll 4
    for (int c = 0; c < 128; ++c)
      u += h2s[r * 129 + c] * (double)sw3[c * 3 + j];
    u = u > 0.0 ? u : 0.0;
    const int s = qb * 16 + r;
    const double po = posd[r * 3 + j];
    const double np_ = tanh(u) + po;
    const size_t rn = (size_t)(p * 128 + 64 + s) * 3 + j;
    const size_t ro = (size_t)(p * 128 + s) * 3 + j;
    ppd[rn] = np_;  ppf[rn] = (float)np_;
    ppd[ro] = po;   ppf[ro] = (float)po;
  }
}

// ---------------------------------------------------------------- kernel C
// Top-9 via u64 keys: key=(bits(d2)&~127)|j (d2>=0 => bits monotone; low 7 bits
// carry idx => lexicographic (d2,idx) == one u64 compare; exact d2 ties resolve
// by idx as jax top_k does). Branch-free ascending sorted-insert:
//   s[k] = (key>=s[k]) ? s[k] : max(key, s[k-1])   (k=8..1), s[0]=min(s[0],key)
// 4 segments x 32 candidates per row; tree merge via LDS (9+9 inserts).
__device__ __forceinline__ void ins9(unsigned long long* s, unsigned long long key) {
  #pragma unroll
  for (int k = 8; k >= 1; --k) {
    const unsigned long long lo = s[k - 1];
    const unsigned long long mx = key > lo ? key : lo;
    s[k] = (key >= s[k]) ? s[k] : mx;
  }
  s[0] = key < s[0] ? key : s[0];
}

__global__ __launch_bounds__(512) void neighbors_k2(const double* __restrict__ ppd,
                                                    int* __restrict__ nbr) {
  __shared__ double PX[128], PY[128], PZ[128];
  __shared__ unsigned long long mbuf[2][128][9];   // 18432 B
  const int p = blockIdx.x, t = threadIdx.x;
  const int row = t & 127, seg = t >> 7;
  if (t < 128) {
    PX[t] = ppd[(p * 128 + t) * 3 + 0];
    PY[t] = ppd[(p * 128 + t) * 3 + 1];
    PZ[t] = ppd[(p * 128 + t) * 3 + 2];
  }
  __syncthreads();
  const double R2d = 0.3 * 0.3;
  const double xi = PX[row], yi = PY[row], zi = PZ[row];
  unsigned long long s[9];
  #pragma unroll
  for (int k = 0; k < 9; ++k) s[k] = SENTK;
  const int j0 = seg * 32;
  for (int jj = 0; jj < 32; ++jj) {
    const int j = j0 + jj;
    const double dx = PX[j] - xi, dy = PY[j] - yi, dz = PZ[j] - zi;
    const double d2 = dx * dx + dy * dy + dz * dz;
    unsigned long long key =
        (((unsigned long long)__double_as_longlong(d2)) & ~127ull) | (unsigned long long)j;
    key = (d2 <= R2d) ? key : SENTK;
    ins9(s, key);
  }
  // segs 1,3 publish partial lists
  if (seg & 1) {
    #pragma unroll
    for (int k = 0; k < 9; ++k) mbuf[seg >> 1][row][k] = s[k];
  }
  __syncthreads();
  // round 1: seg0 absorbs seg1, seg2 absorbs seg3
  if (!(seg & 1)) {
    #pragma unroll
    for (int m = 0; m < 9; ++m) ins9(s, mbuf[seg >> 1][row][m]);
  }
  // seg2 publishes its merged list (own slot: no cross-thread hazard pre-barrier)
  if (seg == 2) {
    #pragma unroll
    for (int k = 0; k < 9; ++k) mbuf[1][row][k] = s[k];
  }
  __syncthreads();
  // round 2: seg0 absorbs seg2's merged list, writes output
  if (seg == 0) {
    #pragma unroll
    for (int m = 0; m < 9; ++m) ins9(s, mbuf[1][row][m]);
    #pragma unroll
    for (int k = 0; k < 9; ++k)
      nbr[(p * 128 + row) * 9 + k] = (s[k] == SENTK) ? -1 : (int)(s[k] & 127);
  }
}

// ---------------------------------------------------------------- kernel W
// Pack mw1[768:896], mw2, mw3(pad N->16), cw2(hi/lo) into MFMA B-fragment order:
// dst[((nt*KT + kt)*64 + lane)*8 + j] = W[kt*32 + (lane>>4)*8 + j][nt*16 + (lane&15)]
__global__ __launch_bounds__(256) void prepack_w(
    const float* __restrict__ mw1, const float* __restrict__ mw2,
    const float* __restrict__ mw3, const float* __restrict__ cw2,
    ushort* __restrict__ W1p, ushort* __restrict__ W2p, ushort* __restrict__ W3p,
    ushort* __restrict__ C2h, ushort* __restrict__ C2l) {
  const int idx = blockIdx.x * 256 + threadIdx.x;
  if (idx < 65536) {                       // W1p: K=128 (kt<4), N=512 (nt<32)
    const int j = idx & 7, l = (idx >> 3) & 63, kt = (idx >> 9) & 3, nt = idx >> 11;
    const int k = kt * 32 + (l >> 4) * 8 + j, n = nt * 16 + (l & 15);
    W1p[idx] = f2bf(mw1[(768 + k) * 512 + n]);
  } else if (idx < 196608) {               // W2p: K=512 (kt<16), N=256 (nt<16)
    const int q = idx - 65536;
    const int j = q & 7, l = (q >> 3) & 63, kt = (q >> 9) & 15, nt = q >> 13;
    const int k = kt * 32 + (l >> 4) * 8 + j, n = nt * 16 + (l & 15);
    W2p[q] = f2bf(mw2[k * 256 + n]);
  } else if (idx < 200704) {               // W3p: K=256 (kt<8), N=9 padded to 16
    const int q = idx - 196608;
    const int j = q & 7, l = (q >> 3) & 63, kt = q >> 9;
    const int k = kt * 32 + (l >> 4) * 8 + j, n = l & 15;
    W3p[q] = (n < 9) ? f2bf(mw3[k * 9 + n]) : (ushort)0;
  } else if (idx < 208896) {               // C2h/C2l: K=64 (kt<2), N=128 (nt<8)
    const int q = idx - 200704;
    const int j = q & 7, l = (q >> 3) & 63, kt = (q >> 9) & 1, nt = q >> 10;
    const int k = kt * 32 + (l >> 4) * 8 + j, n = nt * 16 + (l & 15);
    const float v = cw2[k * 128 + n];
    const ushort hi = f2bf(v);
    C2h[q] = hi;
    C2l[q] = f2bf(v - bf2f(hi));
  }
}

// ---------------------------------------------------------------- kernel D
// Edge MLP via MFMA: 16 pts/block (144 edges, M-tiles=9), N=128, K=64.
#define EPITCH 80    // m1 pitch (ushorts): 160 B rows
#define M2PITCH 132  // m2 pitch (ushorts): 264 B rows
__global__ __launch_bounds__(256) void edge_mfma(
    const float* __restrict__ ppf, const int* __restrict__ nbr,
    const float* __restrict__ cw1, const float* __restrict__ cb1,
    const ushort* __restrict__ C2h, const ushort* __restrict__ C2l,
    const float* __restrict__ cb2, ushort* __restrict__ aggB) {
  __shared__ float posL[128 * 3];
  __shared__ int nbrL[144];
  __shared__ __align__(16) ushort buf[2 * 144 * EPITCH];  // m1h|m1l, reused as m2
  ushort* m1h = buf;
  ushort* m1l = buf + 144 * EPITCH;
  ushort* m2L = buf;   // 144*132 = 19008 <= 23040

  const int b = blockIdx.x, t = threadIdx.x;
  const int p = b >> 3, off = (b & 7) * 16;
  for (int i = t; i < 384; i += 256) posL[i] = ppf[p * 384 + i];
  if (t < 144) nbrL[t] = nbr[(p * 128 + off) * 9 + t];
  __syncthreads();

  // phase 1: m1[e][c] = relu(feat . cw1[:,c] + cb1[c]) -> bf16 hi/lo
  {
    const int c = t & 63, eg = t >> 6;
    float w1c[6];
    #pragma unroll
    for (int q = 0; q < 6; ++q) w1c[q] = cw1[q * 64 + c];
    const float b1c = cb1[c];
    for (int e = eg; e < 144; e += 4) {
      const int pl = e / 9;
      const int j = nbrL[e];
      const int jj = j < 0 ? 0 : j;
      const int ctr = off + pl;
      const float nx = posL[jj * 3], ny = posL[jj * 3 + 1], nz = posL[jj * 3 + 2];
      const float cx = posL[ctr * 3], cy = posL[ctr * 3 + 1], cz = posL[ctr * 3 + 2];
      float v = b1c + nx * w1c[0] + ny * w1c[1] + nz * w1c[2] +
                (nx - cx) * w1c[3] + (ny - cy) * w1c[4] + (nz - cz) * w1c[5];
      v = fmaxf(v, 0.f);
      const ushort hi = f2bf(v);
      m1h[e * EPITCH + c] = hi;
      m1l[e * EPITCH + c] = f2bf(v - bf2f(hi));
    }
  }
  __syncthreads();

  // phase 2: MFMA, wave w covers cols [w*32, w*32+32)
  const int w = t >> 6, l = t & 63, lrow = l & 15, quad = l >> 4;
  ffrag acc[9][2];
  {
    bfrag Bh[2][2], Bl[2][2];  // [nt][kt]
    #pragma unroll
    for (int nt = 0; nt < 2; ++nt)
      #pragma unroll
      for (int kt = 0; kt < 2; ++kt) {
        const int bi = (((w * 2 + nt) * 2 + kt) * 64 + l) * 8;
        Bh[nt][kt] = *(const bfrag*)&C2h[bi];
        Bl[nt][kt] = *(const bfrag*)&C2l[bi];
      }
    #pragma unroll
    for (int mt = 0; mt < 9; ++mt) {
      bfrag Ah[2], Al[2];
      #pragma unroll
      for (int kt = 0; kt < 2; ++kt) {
        const int ai = (mt * 16 + lrow) * EPITCH + kt * 32 + quad * 8;
        Ah[kt] = *(const bfrag*)&m1h[ai];
        Al[kt] = *(const bfrag*)&m1l[ai];
      }
      #pragma unroll
      for (int nt = 0; nt < 2; ++nt) {
        ffrag a = (ffrag){0.f, 0.f, 0.f, 0.f};
        #pragma unroll
        for (int kt = 0; kt < 2; ++kt) {
          a = MFMA16(Ah[kt], Bh[nt][kt], a);
          a = MFMA16(Ah[kt], Bl[nt][kt], a);
          a = MFMA16(Al[kt], Bh[nt][kt], a);
        }
        acc[mt][nt] = a;
      }
    }
  }
  __syncthreads();  // all m1 reads done; buf reusable

  // phase 3: epilogue bias+relu -> bf16 -> m2L
  {
    const float cbv0 = cb2[w * 32 + lrow];
    const float cbv1 = cb2[w * 32 + 16 + lrow];
    #pragma unroll
    for (int mt = 0; mt < 9; ++mt)
      #pragma unroll
      for (int nt = 0; nt < 2; ++nt) {
        const int col = w * 32 + nt * 16 + lrow;
        const float cbv = nt ? cbv1 : cbv0;
        #pragma unroll
        for (int r = 0; r < 4; ++r) {
          const int row = mt * 16 + quad * 4 + r;
          m2L[row * M2PITCH + col] = f2bf(fmaxf(acc[mt][nt][r] + cbv, 0.f));
        }
      }
  }
  __syncthreads();

  // phase 4: max over valid neighbors (ushort compare valid: all values >= 0)
  for (int o = t; o < 2048; o += 256) {
    const int pt = o >> 7, c = o & 127;
    ushort best = 0;
    #pragma unroll
    for (int s = 0; s < 9; ++s) {
      if (nbrL[pt * 9 + s] >= 0) {
        const ushort u = m2L[(pt * 9 + s) * M2PITCH + c];
        best = u > best ? u : best;
      }
    }
    aggB[(size_t)(p * 128 + off + pt) * 128 + c] = best;
  }
}

// ---------------------------------------------------------------- kernel E
// Final MLP via MFMA: 32 rows/block, 1024 blocks. agg bf16.
#define PA  136   // aT pitch (bf16 elems)
#define PG1 520
#define PG2 264
__global__ __launch_bounds__(256) void final_mlp_mfma(
    const ushort* __restrict__ aggB, const float* __restrict__ B1,
    const ushort* __restrict__ W1p, const ushort* __restrict__ W2p,
    const ushort* __restrict__ W3p, const float* __restrict__ mb2,
    const float* __restrict__ mb3, float* __restrict__ rotw,
    float* __restrict__ out_rc) {
  __shared__ __align__(16) ushort g1T[32 * PG1];   // 33280 B
  __shared__ __align__(16) ushort reg2[32 * PG2];  // 16896 B: aT then g2T
  __shared__ float rotL[32 * 9];
  const int b = blockIdx.x, t = threadIdx.x;
  const int w = t >> 6, l = t & 63;
  const int lrow = l & 15, quad = l >> 4;
  int p, off;
  if (b < 512) { p = b >> 1;         off = (b & 1) * 32; }
  else         { p = (b - 512) >> 1; off = 64 + ((b - 512) & 1) * 32; }
  const int n0 = b * 32;

  // ---- stage 0: aggB tile (bf16) -> LDS aT[32][128] pitch PA
  {
    ushort* aT = reg2;
    const int r0 = t >> 3, sg = (t & 7) * 16;
    const ushort* src = aggB + (size_t)(p * 128 + off + r0) * 128 + sg;
    const uint4 v0 = *(const uint4*)src;
    const uint4 v1 = *(const uint4*)(src + 8);
    *(uint4*)&aT[r0 * PA + sg] = v0;
    *(uint4*)&aT[r0 * PA + sg + 8] = v1;
  }
  __syncthreads();

  // ---- stage 1: g1 (M=32, N=512, K=128); wave w: N cols [w*128, w*128+128)
  {
    const ushort* aT = reg2;
    bfrag a[2][4];
    #pragma unroll
    for (int mt = 0; mt < 2; ++mt)
      #pragma unroll
      for (int kt = 0; kt < 4; ++kt)
        a[mt][kt] = *(const bfrag*)&aT[(mt * 16 + lrow) * PA + kt * 32 + quad * 8];
    ffrag acc[2][8];
    #pragma unroll
    for (int nti = 0; nti < 8; ++nti) {
      const float bv = B1[p * 512 + (w * 8 + nti) * 16 + lrow];
      acc[0][nti] = (ffrag){bv, bv, bv, bv};
      acc[1][nti] = acc[0][nti];
    }
    #pragma unroll
    for (int nti = 0; nti < 8; ++nti) {
      const int nt = w * 8 + nti;
      #pragma unroll
      for (int kt = 0; kt < 4; ++kt) {
        const bfrag bb = *(const bfrag*)&W1p[((nt * 4 + kt) * 64 + l) * 8];
        acc[0][nti] = MFMA16(a[0][kt], bb, acc[0][nti]);
        acc[1][nti] = MFMA16(a[1][kt], bb, acc[1][nti]);
      }
    }
    #pragma unroll
    for (int mt = 0; mt < 2; ++mt)
      #pragma unroll
      for (int nti = 0; nti < 8; ++nti) {
        const int col = (w * 8 + nti) * 16 + lrow;
        #pragma unroll
        for (int r = 0; r < 4; ++r)
          g1T[(mt * 16 + quad * 4 + r) * PG1 + col] = f2bf(fmaxf(acc[mt][nti][r], 0.f));
      }
  }
  __syncthreads();

  // ---- stage 2: g2 (M=32, N=256, K=512); wave w: N cols [w*64, w*64+64)
  {
    bfrag a[2][16];
    #pragma unroll
    for (int mt = 0; mt < 2; ++mt)
      #pragma unroll
      for (int kt = 0; kt < 16; ++kt)
        a[mt][kt] = *(const bfrag*)&g1T[(mt * 16 + lrow) * PG1 + kt * 32 + quad * 8];
    ffrag acc[2][4];
    #pragma unroll
    for (int nti = 0; nti < 4; ++nti) {
      acc[0][nti] = (ffrag){0.f, 0.f, 0.f, 0.f};
      acc[1][nti] = acc[0][nti];
    }
    #pragma unroll
    for (int nti = 0; nti < 4; ++nti) {
      const int nt = w * 4 + nti;
      #pragma unroll
      for (int kt = 0; kt < 16; ++kt) {
        const bfrag bb = *(const bfrag*)&W2p[((nt * 16 + kt) * 64 + l) * 8];
        acc[0][nti] = MFMA16(a[0][kt], bb, acc[0][nti]);
        acc[1][nti] = MFMA16(a[1][kt], bb, acc[1][nti]);
      }
    }
    ushort* g2T = reg2;
    #pragma unroll
    for (int mt = 0; mt < 2; ++mt)
      #pragma unroll
      for (int nti = 0; nti < 4; ++nti) {
        const int col = (w * 4 + nti) * 16 + lrow;
        const float bv = mb2[col];
        #pragma unroll
        for (int r = 0; r < 4; ++r)
          g2T[(mt * 16 + quad * 4 + r) * PG2 + col] =
              f2bf(fmaxf(acc[mt][nti][r] + bv, 0.f));
      }
  }
  __syncthreads();

  // ---- stage 3: g3 (M=32, N=16 padded, K=256); waves 0,1 take mt=w
  if (w < 2) {
    const ushort* g2T = reg2;
    ffrag acc = (ffrag){0.f, 0.f, 0.f, 0.f};
    #pragma unroll
    for (int kt = 0; kt < 8; ++kt) {
      const bfrag aa = *(const bfrag*)&g2T[(w * 16 + lrow) * PG2 + kt * 32 + quad * 8];
      const bfrag bb = *(const bfrag*)&W3p[(kt * 64 + l) * 8];
      acc = MFMA16(aa, bb, acc);
    }
    if (lrow < 9) {
      const float bv = mb3[lrow];
      #pragma unroll
      for (int r = 0; r < 4; ++r) {
        const int m = w * 16 + quad * 4 + r;
        const float u = fmaxf(acc[r] + bv, 0.f);
        rotL[m * 9 + lrow] = u;
        rotw[(size_t)(n0 + m) * 9 + lrow] = u;
      }
    }
  }
  __syncthreads();

  // ---- stage 4: rot_constrain
  for (int idx = t; idx < 288; idx += 256) {
    const int r = idx / 9, e = idx % 9, ii = e / 3, jj = e % 3;
    const float* R = &rotL[r * 9];
    out_rc[(size_t)(n0 + r) * 9 + e] =
        R[ii] * R[jj] + R[3 + ii] * R[3 + jj] + R[6 + ii] * R[6 + jj];
  }
}

// ---------------------------------------------------------------- kernel F
__global__ __launch_bounds__(256) void plane_k(const float* __restrict__ rotw,
                                               const float* __restrict__ ppf,
                                               float* __restrict__ out_plane) {
  const int q = blockIdx.x * 256 + threadIdx.x;  // < 524288
  const int n = q >> 4, tt = q & 15;
  const float* R = &rotw[n * 9];
  const int tx = tt & 3, ty = tt >> 2;
  const double step = 0.4 / 3.0;
  const float X = (tx == 3) ? 0.2f : (float)((double)tx * step - 0.2);
  const float Y = (ty == 3) ? 0.2f : (float)((double)ty * step - 0.2);
  const int m = q & (M2N - 1);
  int p, s;
  if (m < NPTS) { p = m >> 6; s = m & 63; }
  else          { const int mm = m - NPTS; p = mm >> 6; s = 64 + (mm & 63); }
  const float* C = &ppf[(p * 128 + s) * 3];
  #pragma unroll
  for (int i2 = 0; i2 < 3; ++i2) {
    const float d = R[i2 * 3 + 0] * X + R[i2 * 3 + 1] * Y;  // npts z == 0
    out_plane[q * 3 + i2] = d + C[i2];
  }
}

// ---------------------------------------------------------------- launch
extern "C" void kernel_launch(void* const* d_in, const int* in_sizes, int n_in,
                              void* d_out, int out_size, void* d_ws, size_t ws_size,
                              hipStream_t stream) {
  const float* pos       = (const float*)d_in[1];
  const float* local_fea = (const float*)d_in[4];
  const float* sw1 = (const float*)d_in[5];
  const float* sb1 = (const float*)d_in[6];
  const float* sw2 = (const float*)d_in[7];
  const float* sb2 = (const float*)d_in[8];
  const float* sw3 = (const float*)d_in[9];
  const float* sb3 = (const float*)d_in[10];
  const float* cw1 = (const float*)d_in[11];
  const float* cb1 = (const float*)d_in[12];
  const float* cw2 = (const float*)d_in[13];
  const float* cb2 = (const float*)d_in[14];
  const float* mw1 = (const float*)d_in[15];
  const float* mb1 = (const float*)d_in[16];
  const float* mw2 = (const float*)d_in[17];
  const float* mb2 = (const float*)d_in[18];
  const float* mw3 = (const float*)d_in[19];
  const float* mb3 = (const float*)d_in[20];

  char* ws = (char*)d_ws;
  double* A1d  = (double*)(ws + 0);         // 524288
  double* ppd  = (double*)(ws + 524288);    // 786432
  float*  B1   = (float*)(ws + 1310720);    // 524288
  float*  ppf  = (float*)(ws + 1835008);    // 393216
  int*    nbr  = (int*)(ws + 2228224);      // 1179648
  ushort* aggB = (ushort*)(ws + 3407872);   // 8388608
  float*  rotw = (float*)(ws + 11796480);   // 1179648
  ushort* W1p  = (ushort*)(ws + 12976128);  // 131072
  ushort* W2p  = (ushort*)(ws + 13107200);  // 262144
  ushort* W3p  = (ushort*)(ws + 13369344);  // 8192
  ushort* C2h  = (ushort*)(ws + 13377536);  // 16384
  ushort* C2l  = (ushort*)(ws + 13393920);  // 16384 (end 13410304)

  float* out_plane = (float*)d_out;
  float* out_rc = out_plane + 1572864;  // P*2048*3

  patch_pre2<<<768, 256, 0, stream>>>(local_fea, sw1, sb1, mw1, mb1, A1d, B1);
  point_mlp5<<<1024, 256, 0, stream>>>(pos, sw1, sw2, sb2, sw3, sb3, A1d, ppd, ppf);
  neighbors_k2<<<256, 512, 0, stream>>>(ppd, nbr);
  prepack_w<<<816, 256, 0, stream>>>(mw1, mw2, mw3, cw2, W1p, W2p, W3p, C2h, C2l);
  edge_mfma<<<2048, 256, 0, stream>>>(ppf, nbr, cw1, cb1, C2h, C2l, cb2, aggB);
  final_mlp_mfma<<<1024, 256, 0, stream>>>(aggB, B1, W1p, W2p, W3p, mb2, mb3, rotw, out_rc);
  plane_k<<<2048, 256, 0, stream>>>(rotw, ppf, out_plane);
}

// Round 9
// 275.344 us; speedup vs baseline: 2.5490x; 1.0330x over previous
//
#include <hip/hip_runtime.h>

// PlanePriorNet: P=256 patches x PT=64 pts, D=768. float32 I/O.
// Round 9: point MLP stage-2 re-mapped: thread=(c-quad, pt-pair) -> per k-iter
// 1 ds_read_b128 + 1 float4 global load + 8 f64 FMA (was 8 ds_read_b64).
// LDS-issue pressure /8 => VALU-bound. Per-acc k-chain order and statement
// form unchanged => bit-identical ppd => identical top-k.

#define P 256
#define PT 64
#define NPTS 16384          // P*PT
#define M2N 32768           // 2*N
#define D 768
#define SENTK 0xFFFFFFFFFFFFFFFFull

typedef __attribute__((ext_vector_type(8))) short bfrag;   // 8 x bf16 (4 VGPR)
typedef __attribute__((ext_vector_type(4))) float ffrag;   // 4 x f32 acc

#define MFMA16(a, b, c) __builtin_amdgcn_mfma_f32_16x16x32_bf16((a), (b), (c), 0, 0, 0)

// round-to-nearest-even fp32 -> bf16
__device__ __forceinline__ ushort f2bf(float x) {
  unsigned u = __float_as_uint(x);
  u = (u + 0x7FFFu + ((u >> 16) & 1u)) >> 16;
  return (ushort)u;
}
__device__ __forceinline__ float bf2f(ushort u) {
  return __uint_as_float((unsigned)u << 16);
}

// ---------------------------------------------------------------- kernel A
// Split by column chunk: chunk 0 -> A1d (fp64, 256 cols); chunks 1,2 -> B1 (fp32).
__global__ __launch_bounds__(256) void patch_pre2(
    const float* __restrict__ lf, const float* __restrict__ sw1,
    const float* __restrict__ sb1, const float* __restrict__ mw1,
    const float* __restrict__ mb1, double* __restrict__ A1d, float* __restrict__ B1) {
  __shared__ float lfs[768];
  const int b = blockIdx.x, t = threadIdx.x;
  const int p = b / 3, chunk = b % 3;
  for (int i = t; i < 768; i += 256) lfs[i] = lf[p * 768 + i];
  __syncthreads();
  if (chunk == 0) {
    double a = (double)sb1[t];
    for (int d = 0; d < 768; ++d)
      a += (double)lfs[d] * (double)sw1[d * 256 + t];
    A1d[p * 256 + t] = a;
  } else {
    const int c = (chunk - 1) * 256 + t;
    float bb = 0.f;
    for (int d = 0; d < 768; ++d)
      bb += lfs[d] * mw1[d * 512 + c];
    B1[p * 512 + c] = mb1[c] + bb;
  }
}

// ---------------------------------------------------------------- kernel B
// Point MLP, fp64, quarter-patch blocks (16 pts, 1024 blocks).
// h1T [256][18] doubles (pitch 18: k*18+2*ptg stays 16B-aligned for b128);
// h2s [16][129] doubles overlays h1T after a barrier.
// Stage 2: thread t -> c-quad c0=t&31 (cols 4c0..4c0+3), pt-pair ptg=t>>5.
__global__ __launch_bounds__(256) void point_mlp6(
    const float* __restrict__ pos, const float* __restrict__ sw1,
    const float* __restrict__ sw2, const float* __restrict__ sb2,
    const float* __restrict__ sw3, const float* __restrict__ sb3,
    const double* __restrict__ A1d, double* __restrict__ ppd, float* __restrict__ ppf) {
  __shared__ double smemD[4608];   // h1T [k][pt] pitch 18 (36864 B); h2s overlay
  __shared__ double posd[48];
  double* h1T = smemD;
  double* h2s = smemD;

  const int b = blockIdx.x, t = threadIdx.x;
  const int p = b >> 2, qb = b & 3;    // pts [qb*16, qb*16+16)
  if (t < 48) posd[t] = (double)pos[p * 192 + qb * 48 + t];
  __syncthreads();

  // stage 1: h1T[k=t][pt] = relu(A1[k] + pos . sw1'[k])   (round-4 expression)
  {
    const double a1 = A1d[p * 256 + t];
    const double w0 = (double)sw1[768 * 256 + t];
    const double w1 = (double)sw1[769 * 256 + t];
    const double w2 = (double)sw1[770 * 256 + t];
    for (int r = 0; r < 16; ++r) {
      const double* pp = &posd[r * 3];
      const double v = a1 + pp[0] * w0 + pp[1] * w1 + pp[2] * w2;
      h1T[t * 18 + r] = v > 0.0 ? v : 0.0;
    }
  }
  __syncthreads();

  // stage 2: h2[pt][c] = relu(sb2 + sum_k h1[pt][k]*sw2[k][c])
  // (per-acc k-chain sequential 0..255, identical statement form => bit-identical)
  {
    const int c0 = t & 31, ptg = t >> 5;
    double acc[2][4];
    #pragma unroll
    for (int i = 0; i < 2; ++i)
      #pragma unroll
      for (int j = 0; j < 4; ++j) acc[i][j] = 0.0;
    const float4* wp = (const float4*)sw2 + c0;   // wf[k] = wp[k*32]
    #pragma unroll 4
    for (int k = 0; k < 256; ++k) {
      const double2 h = *(const double2*)&h1T[k * 18 + ptg * 2];
      const float4 wf = wp[k * 32];
      const double w0 = (double)wf.x, w1 = (double)wf.y;
      const double w2 = (double)wf.z, w3 = (double)wf.w;
      acc[0][0] += h.x * w0;  acc[0][1] += h.x * w1;
      acc[0][2] += h.x * w2;  acc[0][3] += h.x * w3;
      acc[1][0] += h.y * w0;  acc[1][1] += h.y * w1;
      acc[1][2] += h.y * w2;  acc[1][3] += h.y * w3;
    }
    __syncthreads();  // all h1T reads done; overlay h2s
    #pragma unroll
    for (int i = 0; i < 2; ++i) {
      const int pt = ptg * 2 + i;
      #pragma unroll
      for (int j = 0; j < 4; ++j) {
        const int c = c0 * 4 + j;
        const double u = acc[i][j] + (double)sb2[c];
        h2s[pt * 129 + c] = u > 0.0 ? u : 0.0;
      }
    }
  }
  __syncthreads();

  // stage 3: h3 + tanh + writes (48 threads; round-4 sequential c-sum)
  if (t < 48) {
    const int r = t / 3, j = t % 3;
    double u = (double)sb3[j];
    #pragma unroll 4
    for (int c = 0; c < 128; ++c)
      u += h2s[r * 129 + c] * (double)sw3[c * 3 + j];
    u = u > 0.0 ? u : 0.0;
    const int s = qb * 16 + r;
    const double po = posd[r * 3 + j];
    const double np_ = tanh(u) + po;
    const size_t rn = (size_t)(p * 128 + 64 + s) * 3 + j;
    const size_t ro = (size_t)(p * 128 + s) * 3 + j;
    ppd[rn] = np_;  ppf[rn] = (float)np_;
    ppd[ro] = po;   ppf[ro] = (float)po;
  }
}

// ---------------------------------------------------------------- kernel C
// Top-9 via u64 keys: key=(bits(d2)&~127)|j; branch-free sorted-insert;
// 4 segments x 32 candidates per row; tree merge via LDS (9+9 inserts).
__device__ __forceinline__ void ins9(unsigned long long* s, unsigned long long key) {
  #pragma unroll
  for (int k = 8; k >= 1; --k) {
    const unsigned long long lo = s[k - 1];
    const unsigned long long mx = key > lo ? key : lo;
    s[k] = (key >= s[k]) ? s[k] : mx;
  }
  s[0] = key < s[0] ? key : s[0];
}

__global__ __launch_bounds__(512) void neighbors_k2(const double* __restrict__ ppd,
                                                    int* __restrict__ nbr) {
  __shared__ double PX[128], PY[128], PZ[128];
  __shared__ unsigned long long mbuf[2][128][9];   // 18432 B
  const int p = blockIdx.x, t = threadIdx.x;
  const int row = t & 127, seg = t >> 7;
  if (t < 128) {
    PX[t] = ppd[(p * 128 + t) * 3 + 0];
    PY[t] = ppd[(p * 128 + t) * 3 + 1];
    PZ[t] = ppd[(p * 128 + t) * 3 + 2];
  }
  __syncthreads();
  const double R2d = 0.3 * 0.3;
  const double xi = PX[row], yi = PY[row], zi = PZ[row];
  unsigned long long s[9];
  #pragma unroll
  for (int k = 0; k < 9; ++k) s[k] = SENTK;
  const int j0 = seg * 32;
  for (int jj = 0; jj < 32; ++jj) {
    const int j = j0 + jj;
    const double dx = PX[j] - xi, dy = PY[j] - yi, dz = PZ[j] - zi;
    const double d2 = dx * dx + dy * dy + dz * dz;
    unsigned long long key =
        (((unsigned long long)__double_as_longlong(d2)) & ~127ull) | (unsigned long long)j;
    key = (d2 <= R2d) ? key : SENTK;
    ins9(s, key);
  }
  if (seg & 1) {
    #pragma unroll
    for (int k = 0; k < 9; ++k) mbuf[seg >> 1][row][k] = s[k];
  }
  __syncthreads();
  if (!(seg & 1)) {
    #pragma unroll
    for (int m = 0; m < 9; ++m) ins9(s, mbuf[seg >> 1][row][m]);
  }
  if (seg == 2) {
    #pragma unroll
    for (int k = 0; k < 9; ++k) mbuf[1][row][k] = s[k];
  }
  __syncthreads();
  if (seg == 0) {
    #pragma unroll
    for (int m = 0; m < 9; ++m) ins9(s, mbuf[1][row][m]);
    #pragma unroll
    for (int k = 0; k < 9; ++k)
      nbr[(p * 128 + row) * 9 + k] = (s[k] == SENTK) ? -1 : (int)(s[k] & 127);
  }
}

// ---------------------------------------------------------------- kernel W
// Pack mw1[768:896], mw2, mw3(pad N->16), cw2(hi/lo) into MFMA B-fragment order:
// dst[((nt*KT + kt)*64 + lane)*8 + j] = W[kt*32 + (lane>>4)*8 + j][nt*16 + (lane&15)]
__global__ __launch_bounds__(256) void prepack_w(
    const float* __restrict__ mw1, const float* __restrict__ mw2,
    const float* __restrict__ mw3, const float* __restrict__ cw2,
    ushort* __restrict__ W1p, ushort* __restrict__ W2p, ushort* __restrict__ W3p,
    ushort* __restrict__ C2h, ushort* __restrict__ C2l) {
  const int idx = blockIdx.x * 256 + threadIdx.x;
  if (idx < 65536) {                       // W1p: K=128 (kt<4), N=512 (nt<32)
    const int j = idx & 7, l = (idx >> 3) & 63, kt = (idx >> 9) & 3, nt = idx >> 11;
    const int k = kt * 32 + (l >> 4) * 8 + j, n = nt * 16 + (l & 15);
    W1p[idx] = f2bf(mw1[(768 + k) * 512 + n]);
  } else if (idx < 196608) {               // W2p: K=512 (kt<16), N=256 (nt<16)
    const int q = idx - 65536;
    const int j = q & 7, l = (q >> 3) & 63, kt = (q >> 9) & 15, nt = q >> 13;
    const int k = kt * 32 + (l >> 4) * 8 + j, n = nt * 16 + (l & 15);
    W2p[q] = f2bf(mw2[k * 256 + n]);
  } else if (idx < 200704) {               // W3p: K=256 (kt<8), N=9 padded to 16
    const int q = idx - 196608;
    const int j = q & 7, l = (q >> 3) & 63, kt = q >> 9;
    const int k = kt * 32 + (l >> 4) * 8 + j, n = l & 15;
    W3p[q] = (n < 9) ? f2bf(mw3[k * 9 + n]) : (ushort)0;
  } else if (idx < 208896) {               // C2h/C2l: K=64 (kt<2), N=128 (nt<8)
    const int q = idx - 200704;
    const int j = q & 7, l = (q >> 3) & 63, kt = (q >> 9) & 1, nt = q >> 10;
    const int k = kt * 32 + (l >> 4) * 8 + j, n = nt * 16 + (l & 15);
    const float v = cw2[k * 128 + n];
    const ushort hi = f2bf(v);
    C2h[q] = hi;
    C2l[q] = f2bf(v - bf2f(hi));
  }
}

// ---------------------------------------------------------------- kernel D
// Edge MLP via MFMA: 16 pts/block (144 edges, M-tiles=9), N=128, K=64.
#define EPITCH 80    // m1 pitch (ushorts): 160 B rows
#define M2PITCH 132  // m2 pitch (ushorts): 264 B rows
__global__ __launch_bounds__(256) void edge_mfma(
    const float* __restrict__ ppf, const int* __restrict__ nbr,
    const float* __restrict__ cw1, const float* __restrict__ cb1,
    const ushort* __restrict__ C2h, const ushort* __restrict__ C2l,
    const float* __restrict__ cb2, ushort* __restrict__ aggB) {
  __shared__ float posL[128 * 3];
  __shared__ int nbrL[144];
  __shared__ __align__(16) ushort buf[2 * 144 * EPITCH];  // m1h|m1l, reused as m2
  ushort* m1h = buf;
  ushort* m1l = buf + 144 * EPITCH;
  ushort* m2L = buf;   // 144*132 = 19008 <= 23040

  const int b = blockIdx.x, t = threadIdx.x;
  const int p = b >> 3, off = (b & 7) * 16;
  for (int i = t; i < 384; i += 256) posL[i] = ppf[p * 384 + i];
  if (t < 144) nbrL[t] = nbr[(p * 128 + off) * 9 + t];
  __syncthreads();

  // phase 1: m1[e][c] = relu(feat . cw1[:,c] + cb1[c]) -> bf16 hi/lo
  {
    const int c = t & 63, eg = t >> 6;
    float w1c[6];
    #pragma unroll
    for (int q = 0; q < 6; ++q) w1c[q] = cw1[q * 64 + c];
    const float b1c = cb1[c];
    for (int e = eg; e < 144; e += 4) {
      const int pl = e / 9;
      const int j = nbrL[e];
      const int jj = j < 0 ? 0 : j;
      const int ctr = off + pl;
      const float nx = posL[jj * 3], ny = posL[jj * 3 + 1], nz = posL[jj * 3 + 2];
      const float cx = posL[ctr * 3], cy = posL[ctr * 3 + 1], cz = posL[ctr * 3 + 2];
      float v = b1c + nx * w1c[0] + ny * w1c[1] + nz * w1c[2] +
                (nx - cx) * w1c[3] + (ny - cy) * w1c[4] + (nz - cz) * w1c[5];
      v = fmaxf(v, 0.f);
      const ushort hi = f2bf(v);
      m1h[e * EPITCH + c] = hi;
      m1l[e * EPITCH + c] = f2bf(v - bf2f(hi));
    }
  }
  __syncthreads();

  // phase 2: MFMA, wave w covers cols [w*32, w*32+32)
  const int w = t >> 6, l = t & 63, lrow = l & 15, quad = l >> 4;
  ffrag acc[9][2];
  {
    bfrag Bh[2][2], Bl[2][2];  // [nt][kt]
    #pragma unroll
    for (int nt = 0; nt < 2; ++nt)
      #pragma unroll
      for (int kt = 0; kt < 2; ++kt) {
        const int bi = (((w * 2 + nt) * 2 + kt) * 64 + l) * 8;
        Bh[nt][kt] = *(const bfrag*)&C2h[bi];
        Bl[nt][kt] = *(const bfrag*)&C2l[bi];
      }
    #pragma unroll
    for (int mt = 0; mt < 9; ++mt) {
      bfrag Ah[2], Al[2];
      #pragma unroll
      for (int kt = 0; kt < 2; ++kt) {
        const int ai = (mt * 16 + lrow) * EPITCH + kt * 32 + quad * 8;
        Ah[kt] = *(const bfrag*)&m1h[ai];
        Al[kt] = *(const bfrag*)&m1l[ai];
      }
      #pragma unroll
      for (int nt = 0; nt < 2; ++nt) {
        ffrag a = (ffrag){0.f, 0.f, 0.f, 0.f};
        #pragma unroll
        for (int kt = 0; kt < 2; ++kt) {
          a = MFMA16(Ah[kt], Bh[nt][kt], a);
          a = MFMA16(Ah[kt], Bl[nt][kt], a);
          a = MFMA16(Al[kt], Bh[nt][kt], a);
        }
        acc[mt][nt] = a;
      }
    }
  }
  __syncthreads();  // all m1 reads done; buf reusable

  // phase 3: epilogue bias+relu -> bf16 -> m2L
  {
    const float cbv0 = cb2[w * 32 + lrow];
    const float cbv1 = cb2[w * 32 + 16 + lrow];
    #pragma unroll
    for (int mt = 0; mt < 9; ++mt)
      #pragma unroll
      for (int nt = 0; nt < 2; ++nt) {
        const int col = w * 32 + nt * 16 + lrow;
        const float cbv = nt ? cbv1 : cbv0;
        #pragma unroll
        for (int r = 0; r < 4; ++r) {
          const int row = mt * 16 + quad * 4 + r;
          m2L[row * M2PITCH + col] = f2bf(fmaxf(acc[mt][nt][r] + cbv, 0.f));
        }
      }
  }
  __syncthreads();

  // phase 4: max over valid neighbors (ushort compare valid: all values >= 0)
  for (int o = t; o < 2048; o += 256) {
    const int pt = o >> 7, c = o & 127;
    ushort best = 0;
    #pragma unroll
    for (int s = 0; s < 9; ++s) {
      if (nbrL[pt * 9 + s] >= 0) {
        const ushort u = m2L[(pt * 9 + s) * M2PITCH + c];
        best = u > best ? u : best;
      }
    }
    aggB[(size_t)(p * 128 + off + pt) * 128 + c] = best;
  }
}

// ---------------------------------------------------------------- kernel E
// Final MLP via MFMA: 32 rows/block, 1024 blocks. agg bf16.
#define PA  136   // aT pitch (bf16 elems)
#define PG1 520
#define PG2 264
__global__ __launch_bounds__(256) void final_mlp_mfma(
    const ushort* __restrict__ aggB, const float* __restrict__ B1,
    const ushort* __restrict__ W1p, const ushort* __restrict__ W2p,
    const ushort* __restrict__ W3p, const float* __restrict__ mb2,
    const float* __restrict__ mb3, float* __restrict__ rotw,
    float* __restrict__ out_rc) {
  __shared__ __align__(16) ushort g1T[32 * PG1];   // 33280 B
  __shared__ __align__(16) ushort reg2[32 * PG2];  // 16896 B: aT then g2T
  __shared__ float rotL[32 * 9];
  const int b = blockIdx.x, t = threadIdx.x;
  const int w = t >> 6, l = t & 63;
  const int lrow = l & 15, quad = l >> 4;
  int p, off;
  if (b < 512) { p = b >> 1;         off = (b & 1) * 32; }
  else         { p = (b - 512) >> 1; off = 64 + ((b - 512) & 1) * 32; }
  const int n0 = b * 32;

  // ---- stage 0: aggB tile (bf16) -> LDS aT[32][128] pitch PA
  {
    ushort* aT = reg2;
    const int r0 = t >> 3, sg = (t & 7) * 16;
    const ushort* src = aggB + (size_t)(p * 128 + off + r0) * 128 + sg;
    const uint4 v0 = *(const uint4*)src;
    const uint4 v1 = *(const uint4*)(src + 8);
    *(uint4*)&aT[r0 * PA + sg] = v0;
    *(uint4*)&aT[r0 * PA + sg + 8] = v1;
  }
  __syncthreads();

  // ---- stage 1: g1 (M=32, N=512, K=128); wave w: N cols [w*128, w*128+128)
  {
    const ushort* aT = reg2;
    bfrag a[2][4];
    #pragma unroll
    for (int mt = 0; mt < 2; ++mt)
      #pragma unroll
      for (int kt = 0; kt < 4; ++kt)
        a[mt][kt] = *(const bfrag*)&aT[(mt * 16 + lrow) * PA + kt * 32 + quad * 8];
    ffrag acc[2][8];
    #pragma unroll
    for (int nti = 0; nti < 8; ++nti) {
      const float bv = B1[p * 512 + (w * 8 + nti) * 16 + lrow];
      acc[0][nti] = (ffrag){bv, bv, bv, bv};
      acc[1][nti] = acc[0][nti];
    }
    #pragma unroll
    for (int nti = 0; nti < 8; ++nti) {
      const int nt = w * 8 + nti;
      #pragma unroll
      for (int kt = 0; kt < 4; ++kt) {
        const bfrag bb = *(const bfrag*)&W1p[((nt * 4 + kt) * 64 + l) * 8];
        acc[0][nti] = MFMA16(a[0][kt], bb, acc[0][nti]);
        acc[1][nti] = MFMA16(a[1][kt], bb, acc[1][nti]);
      }
    }
    #pragma unroll
    for (int mt = 0; mt < 2; ++mt)
      #pragma unroll
      for (int nti = 0; nti < 8; ++nti) {
        const int col = (w * 8 + nti) * 16 + lrow;
        #pragma unroll
        for (int r = 0; r < 4; ++r)
          g1T[(mt * 16 + quad * 4 + r) * PG1 + col] = f2bf(fmaxf(acc[mt][nti][r], 0.f));
      }
  }
  __syncthreads();

  // ---- stage 2: g2 (M=32, N=256, K=512); wave w: N cols [w*64, w*64+64)
  {
    bfrag a[2][16];
    #pragma unroll
    for (int mt = 0; mt < 2; ++mt)
      #pragma unroll
      for (int kt = 0; kt < 16; ++kt)
        a[mt][kt] = *(const bfrag*)&g1T[(mt * 16 + lrow) * PG1 + kt * 32 + quad * 8];
    ffrag acc[2][4];
    #pragma unroll
    for (int nti = 0; nti < 4; ++nti) {
      acc[0][nti] = (ffrag){0.f, 0.f, 0.f, 0.f};
      acc[1][nti] = acc[0][nti];
    }
    #pragma unroll
    for (int nti = 0; nti < 4; ++nti) {
      const int nt = w * 4 + nti;
      #pragma unroll
      for (int kt = 0; kt < 16; ++kt) {
        const bfrag bb = *(const bfrag*)&W2p[((nt * 16 + kt) * 64 + l) * 8];
        acc[0][nti] = MFMA16(a[0][kt], bb, acc[0][nti]);
        acc[1][nti] = MFMA16(a[1][kt], bb, acc[1][nti]);
      }
    }
    ushort* g2T = reg2;
    #pragma unroll
    for (int mt = 0; mt < 2; ++mt)
      #pragma unroll
      for (int nti = 0; nti < 4; ++nti) {
        const int col = (w * 4 + nti) * 16 + lrow;
        const float bv = mb2[col];
        #pragma unroll
        for (int r = 0; r < 4; ++r)
          g2T[(mt * 16 + quad * 4 + r) * PG2 + col] =
              f2bf(fmaxf(acc[mt][nti][r] + bv, 0.f));
      }
  }
  __syncthreads();

  // ---- stage 3: g3 (M=32, N=16 padded, K=256); waves 0,1 take mt=w
  if (w < 2) {
    const ushort* g2T = reg2;
    ffrag acc = (ffrag){0.f, 0.f, 0.f, 0.f};
    #pragma unroll
    for (int kt = 0; kt < 8; ++kt) {
      const bfrag aa = *(const bfrag*)&g2T[(w * 16 + lrow) * PG2 + kt * 32 + quad * 8];
      const bfrag bb = *(const bfrag*)&W3p[(kt * 64 + l) * 8];
      acc = MFMA16(aa, bb, acc);
    }
    if (lrow < 9) {
      const float bv = mb3[lrow];
      #pragma unroll
      for (int r = 0; r < 4; ++r) {
        const int m = w * 16 + quad * 4 + r;
        const float u = fmaxf(acc[r] + bv, 0.f);
        rotL[m * 9 + lrow] = u;
        rotw[(size_t)(n0 + m) * 9 + lrow] = u;
      }
    }
  }
  __syncthreads();

  // ---- stage 4: rot_constrain
  for (int idx = t; idx < 288; idx += 256) {
    const int r = idx / 9, e = idx % 9, ii = e / 3, jj = e % 3;
    const float* R = &rotL[r * 9];
    out_rc[(size_t)(n0 + r) * 9 + e] =
        R[ii] * R[jj] + R[3 + ii] * R[3 + jj] + R[6 + ii] * R[6 + jj];
  }
}

// ---------------------------------------------------------------- kernel F
__global__ __launch_bounds__(256) void plane_k(const float* __restrict__ rotw,
                                               const float* __restrict__ ppf,
                                               float* __restrict__ out_plane) {
  const int q = blockIdx.x * 256 + threadIdx.x;  // < 524288
  const int n = q >> 4, tt = q & 15;
  const float* R = &rotw[n * 9];
  const int tx = tt & 3, ty = tt >> 2;
  const double step = 0.4 / 3.0;
  const float X = (tx == 3) ? 0.2f : (float)((double)tx * step - 0.2);
  const float Y = (ty == 3) ? 0.2f : (float)((double)ty * step - 0.2);
  const int m = q & (M2N - 1);
  int p, s;
  if (m < NPTS) { p = m >> 6; s = m & 63; }
  else          { const int mm = m - NPTS; p = mm >> 6; s = 64 + (mm & 63); }
  const float* C = &ppf[(p * 128 + s) * 3];
  #pragma unroll
  for (int i2 = 0; i2 < 3; ++i2) {
    const float d = R[i2 * 3 + 0] * X + R[i2 * 3 + 1] * Y;  // npts z == 0
    out_plane[q * 3 + i2] = d + C[i2];
  }
}

// ---------------------------------------------------------------- launch
extern "C" void kernel_launch(void* const* d_in, const int* in_sizes, int n_in,
                              void* d_out, int out_size, void* d_ws, size_t ws_size,
                              hipStream_t stream) {
  const float* pos       = (const float*)d_in[1];
  const float* local_fea = (const float*)d_in[4];
  const float* sw1 = (const float*)d_in[5];
  const float* sb1 = (const float*)d_in[6];
  const float* sw2 = (const float*)d_in[7];
  const float* sb2 = (const float*)d_in[8];
  const float* sw3 = (const float*)d_in[9];
  const float* sb3 = (const float*)d_in[10];
  const float* cw1 = (const float*)d_in[11];
  const float* cb1 = (const float*)d_in[12];
  const float* cw2 = (const float*)d_in[13];
  const float* cb2 = (const float*)d_in[14];
  const float* mw1 = (const float*)d_in[15];
  const float* mb1 = (const float*)d_in[16];
  const float* mw2 = (const float*)d_in[17];
  const float* mb2 = (const float*)d_in[18];
  const float* mw3 = (const float*)d_in[19];
  const float* mb3 = (const float*)d_in[20];

  char* ws = (char*)d_ws;
  double* A1d  = (double*)(ws + 0);         // 524288
  double* ppd  = (double*)(ws + 524288);    // 786432
  float*  B1   = (float*)(ws + 1310720);    // 524288
  float*  ppf  = (float*)(ws + 1835008);    // 393216
  int*    nbr  = (int*)(ws + 2228224);      // 1179648
  ushort* aggB = (ushort*)(ws + 3407872);   // 8388608
  float*  rotw = (float*)(ws + 11796480);   // 1179648
  ushort* W1p  = (ushort*)(ws + 12976128);  // 131072
  ushort* W2p  = (ushort*)(ws + 13107200);  // 262144
  ushort* W3p  = (ushort*)(ws + 13369344);  // 8192
  ushort* C2h  = (ushort*)(ws + 13377536);  // 16384
  ushort* C2l  = (ushort*)(ws + 13393920);  // 16384 (end 13410304)

  float* out_plane = (float*)d_out;
  float* out_rc = out_plane + 1572864;  // P*2048*3

  patch_pre2<<<768, 256, 0, stream>>>(local_fea, sw1, sb1, mw1, mb1, A1d, B1);
  point_mlp6<<<1024, 256, 0, stream>>>(pos, sw1, sw2, sb2, sw3, sb3, A1d, ppd, ppf);
  neighbors_k2<<<256, 512, 0, stream>>>(ppd, nbr);
  prepack_w<<<816, 256, 0, stream>>>(mw1, mw2, mw3, cw2, W1p, W2p, W3p, C2h, C2l);
  edge_mfma<<<2048, 256, 0, stream>>>(ppf, nbr, cw1, cb1, C2h, C2l, cb2, aggB);
  final_mlp_mfma<<<1024, 256, 0, stream>>>(aggB, B1, W1p, W2p, W3p, mb2, mb3, rotw, out_rc);
  plane_k<<<2048, 256, 0, stream>>>(rotw, ppf, out_plane);
}